// Round 11
// baseline (319.576 us; speedup 1.0000x reference)
//
#include <hip/hip_runtime.h>
#include <math.h>

// ---------------------------------------------------------------------------
// QASS Multihead Attention, MI355X (gfx950)
// B=2, N=2048, D=1024, H=16, Dh=64, HID=64. Output fp32 [B,N,D].
//
// R16: k_attn BARRIER-FREE. Observation: the K-fragment LDS addresses are
//      lane-only -- all 4 waves read IDENTICAL K fragments. So load K
//      global->reg directly from kswz (L2-resident; byte-identical data),
//      register-double-buffered one tile ahead (kfA/kfB, unroll-2 loop).
//      Deletes ALL LDS and ALL __syncthreads from k_attn: no per-tile
//      vmcnt(0) drain, no 4-wave lockstep convoy; waves free-run.
//      k_gemm keeps R15 (BK=32 dbuf K-loop + LDS-staged z=1/z=2 epilogue);
//      k_attn softmax keeps R14 (in-register P, rsum ones-MFMA, cvt_pk).
// Precision: fp16 projections/QK^T, bf16 P*V and O-partials, fp32 softmax
// (deferred, log2 domain; exp2 never overflows fp32).
// ---------------------------------------------------------------------------

typedef _Float16 half_t;
using half8   = __attribute__((ext_vector_type(8))) _Float16;  // 4 VGPRs
using bhalf8  = __attribute__((ext_vector_type(8))) short;     // 8 bf16
using floatx4 = __attribute__((ext_vector_type(4))) float;     // MFMA C/D

__device__ inline unsigned short f2bf(float f) {
  union { float f; unsigned int u; } v; v.f = f;
  unsigned int u = v.u;
  u = u + 0x7fffu + ((u >> 16) & 1u);
  return (unsigned short)(u >> 16);
}
__device__ inline float bf2f(unsigned short h) {
  union { unsigned int u; float f; } v; v.u = ((unsigned int)h) << 16;
  return v.f;
}
__device__ inline float gelu_f(float x) {      // exact (erf) GELU
  return 0.5f * x * (1.0f + erff(x * 0.70710678118654752440f));
}
__device__ __forceinline__ unsigned int cvtpk_bf16(float lo, float hi) {
  unsigned int r;
  asm("v_cvt_pk_bf16_f32 %0, %1, %2" : "=v"(r) : "v"(lo), "v"(hi));
  return r;
}

#define MFMAF16(a, b, c)  __builtin_amdgcn_mfma_f32_16x16x32_f16((a), (b), (c), 0, 0, 0)
#define MFMABF16(a, b, c) __builtin_amdgcn_mfma_f32_16x16x32_bf16((a), (b), (c), 0, 0, 0)

__device__ __forceinline__ void dma16(const void* g, void* l) {
  __builtin_amdgcn_global_load_lds(
      (const __attribute__((address_space(1))) unsigned int*)g,
      (__attribute__((address_space(3))) unsigned int*)l, 16, 0, 0);
}

// ---------------------------------------------------------------------------
// fp32->fp16 conversion (q/k/v 3x4M + weights 4x1M) and (blocks >= 8192)
// base[1024] = gelu(log(n) * wb1) @ wb2.T
// ---------------------------------------------------------------------------
__global__ __launch_bounds__(256) void k_cvtbase(
    const float* __restrict__ q, const float* __restrict__ k, const float* __restrict__ v,
    const float* __restrict__ wq, const float* __restrict__ wk,
    const float* __restrict__ wv, const float* __restrict__ wo,
    half_t* __restrict__ q16, half_t* __restrict__ k16, half_t* __restrict__ v16,
    half_t* __restrict__ w16,
    const float* __restrict__ wb1, const float* __restrict__ wb2,
    const int* __restrict__ nctx, float* __restrict__ base_out) {
  int tid = threadIdx.x;
  if (blockIdx.x >= 8192) {                    // base path (4 blocks)
    __shared__ float h1[64];
    float logn = logf((float)(*nctx));
    if (tid < 64) h1[tid] = gelu_f(logn * wb1[tid]);
    __syncthreads();
    int i = (blockIdx.x - 8192) * 256 + tid;
    float s = 0.f;
#pragma unroll
    for (int j = 0; j < 64; j++) s += h1[j] * wb2[i * 64 + j];
    base_out[i] = s;
    return;
  }
  size_t e = ((size_t)blockIdx.x * 256 + tid) * 8;
  const float* src; half_t* dst; size_t off;
  if (e < (size_t)3 * 4194304) {
    int t = (int)(e >> 22); off = e & 4194303;
    src = (t == 0) ? q : (t == 1 ? k : v);
    dst = (t == 0) ? q16 : (t == 1 ? k16 : v16);
  } else {
    size_t e2 = e - (size_t)3 * 4194304;
    int t = (int)(e2 >> 20); off = (e2 & 1048575);
    src = (t == 0) ? wq : (t == 1 ? wk : (t == 2 ? wv : wo));
    dst = w16 + (size_t)t * 1048576;
  }
  float4 a = *(const float4*)(src + off);
  float4 b = *(const float4*)(src + off + 4);
  half8 h;
  h[0] = (half_t)a.x; h[1] = (half_t)a.y; h[2] = (half_t)a.z; h[3] = (half_t)a.w;
  h[4] = (half_t)b.x; h[5] = (half_t)b.y; h[6] = (half_t)b.z; h[7] = (half_t)b.w;
  *(half8*)(dst + off) = h;
}

// ---------------------------------------------------------------------------
// fp16 GEMM  C[4096,1024] = A @ W^T, 128x128 tile, BK=32, 4 waves (2x2),
// each wave 64x64 (4x4 frags). BK=32 double-buffered global_load_lds
// staging (2 x 16KB = 32KB): per step {barrier; issue DMA(kk+32 -> buf^1);
// compute buf}. After the K-loop the 32KB LDS is reused as an epilogue
// transpose buffer for z=1/z=2 (output-linear staging, then 8x coalesced
// 16B stores/thread).
// MODE 0 (QKV, grid.z selects): z=0 -> qp16 [B,H,N,Dh] fp16 (direct)
//                               z=1 -> kswz fp16 (chunk-swizzled d)
//                               z=2 -> vtl bf16, fragment-linear per tile
//   for the k-permuted PV: key nn (in tile) decomposes kc4=nn>>5,
//   quad=(nn>>2)&3, j=(nn&3)|(((nn>>4)&1)<<2); cell [kc4][lane=quad*16+lm]
//   [dt][j] holds V[key][d=dt*16+lm] (64B/lane contiguous per kc4).
// MODE 3: A=obf fp16 [4096,1024], -> fp32 out (direct)
// ---------------------------------------------------------------------------
template <int MODE>
__global__ __launch_bounds__(256, 3) void k_gemm(const half_t* __restrict__ Abase,
                                                 const half_t* __restrict__ Wbase,
                                                 half_t* __restrict__ qp16,
                                                 half_t* __restrict__ kswz,
                                                 unsigned short* __restrict__ vtl,
                                                 float* __restrict__ outf) {
  const int z = (MODE == 0) ? blockIdx.z : 0;
  const half_t* Ag = Abase + (size_t)z * 4194304;
  const half_t* Wg = Wbase + (size_t)z * 1048576;
  __shared__ __align__(16) half_t SM[4][128 * 32];   // A0,A1,B0,B1; 32 KB
  const int tid = threadIdx.x, lane = tid & 63, w = tid >> 6;
  const int quad = lane >> 4, lm = lane & 15;
  const int wm = w >> 1, wn = w & 1;
  const int bm0 = blockIdx.y * 128, bn0 = blockIdx.x * 128;

  const floatx4 zero4 = {0.f, 0.f, 0.f, 0.f};
  floatx4 acc[4][4];
#pragma unroll
  for (int i = 0; i < 4; i++)
#pragma unroll
    for (int j = 0; j < 4; j++) acc[i][j] = zero4;

  // staging constants (lane-only; bijective per 16-row group)
  const int j4 = lane >> 2;                              // 0..15
  const int cs = (lane & 3) ^ (((j4 & 3) + (j4 >> 2)) & 3);
  const int ub = ((lm & 3) + (lm >> 2)) & 3;             // read-side XOR

  // prologue: stage kk=0 -> buf 0
#pragma unroll
  for (int i = 0; i < 2; i++) {
    int tr = w * 32 + i * 16 + j4;
    dma16((const char*)Ag + ((size_t)(bm0 + tr) * 1024 + cs * 8) * 2,
          (char*)SM[0] + (w * 32 + i * 16) * 64);
    dma16((const char*)Wg + ((size_t)(bn0 + tr) * 1024 + cs * 8) * 2,
          (char*)SM[2] + (w * 32 + i * 16) * 64);
  }

  for (int kk = 0; kk < 1024; kk += 32) {
    const int cur = (kk >> 5) & 1;
    __syncthreads();                 // drains this wave's DMA (buf[cur]) and
                                     // syncs all waves' reads of buf[cur^1]
    if (kk < 992) {
#pragma unroll
      for (int i = 0; i < 2; i++) {
        int tr = w * 32 + i * 16 + j4;
        dma16((const char*)Ag + ((size_t)(bm0 + tr) * 1024 + kk + 32 + cs * 8) * 2,
              (char*)SM[cur ^ 1] + (w * 32 + i * 16) * 64);
        dma16((const char*)Wg + ((size_t)(bn0 + tr) * 1024 + kk + 32 + cs * 8) * 2,
              (char*)SM[2 + (cur ^ 1)] + (w * 32 + i * 16) * 64);
      }
    }

    const half_t* as_ = SM[cur];
    const half_t* bs_ = SM[2 + cur];
    half8 af[4], bf[4];
#pragma unroll
    for (int tm = 0; tm < 4; tm++)
      af[tm] = *(const half8*)&as_[(wm * 64 + tm * 16 + lm) * 32
                                   + ((quad ^ ub) << 3)];
#pragma unroll
    for (int tn = 0; tn < 4; tn++)
      bf[tn] = *(const half8*)&bs_[(wn * 64 + tn * 16 + lm) * 32
                                   + ((quad ^ ub) << 3)];
#pragma unroll
    for (int tm = 0; tm < 4; tm++)
#pragma unroll
      for (int tn = 0; tn < 4; tn++)
        acc[tm][tn] = MFMAF16(af[tm], bf[tn], acc[tm][tn]);
  }

  // ---- epilogue ----
  if constexpr (MODE == 3) {
#pragma unroll
    for (int tm = 0; tm < 4; tm++)
#pragma unroll
      for (int tn = 0; tn < 4; tn++)
#pragma unroll
        for (int rr = 0; rr < 4; rr++) {
          int gm = bm0 + wm * 64 + tm * 16 + quad * 4 + rr;
          int gn = bn0 + wn * 64 + tn * 16 + lm;
          outf[(size_t)gm * 1024 + gn] = acc[tm][tn][rr];
        }
  } else if (z == 0) {
    // direct fp16 stores (per-instruction footprint: 4 x 32B lines -- ok)
#pragma unroll
    for (int tm = 0; tm < 4; tm++)
#pragma unroll
      for (int tn = 0; tn < 4; tn++)
#pragma unroll
        for (int rr = 0; rr < 4; rr++) {
          int gm = bm0 + wm * 64 + tm * 16 + quad * 4 + rr;   // b*2048+n
          int gn = bn0 + wn * 64 + tn * 16 + lm;              // h*64+d
          int b = gm >> 11, n = gm & 2047, hd = gn >> 6, d = gn & 63;
          qp16[((size_t)((b << 4) + hd) * 2048 + n) * 64 + d] = (half_t)acc[tm][tn][rr];
        }
  } else if (z == 1) {
    // LDS-staged: sm[(hl*128+nl)*64 + swz] then linear 16B writes
    half_t* smh = (half_t*)&SM[0][0];
    __syncthreads();                 // K-loop LDS reads complete
#pragma unroll
    for (int tm = 0; tm < 4; tm++)
#pragma unroll
      for (int tn = 0; tn < 4; tn++) {
        int gnl = wn * 64 + tn * 16 + lm;          // local gn 0..127
        int hl = gnl >> 6, d = gnl & 63;
#pragma unroll
        for (int rr = 0; rr < 4; rr++) {
          int nl = wm * 64 + tm * 16 + quad * 4 + rr;
          int sw = ((((d >> 3) ^ (nl & 7)) << 3) | (d & 7));
          smh[(hl * 128 + nl) * 64 + sw] = (half_t)acc[tm][tn][rr];
        }
      }
    __syncthreads();
    {
      const int b = bm0 >> 11, n0 = bm0 & 2047, hd0 = bn0 >> 6;
#pragma unroll
      for (int c = 0; c < 8; c++) {
        int lin = (c * 256 + tid) * 8;
        int hl = lin >> 13, nl = (lin >> 6) & 127, j0 = lin & 63;
        size_t row = (size_t)((b << 4) + hd0 + hl) * 2048 + n0 + nl;
        *(half8*)(kswz + row * 64 + j0) = *(const half8*)(smh + lin);
      }
    }
  } else {
    // z == 2: LDS-staged, rr-packed 8B writes, then linear 16B writes
    unsigned short* sm = (unsigned short*)&SM[0][0];
    __syncthreads();                 // K-loop LDS reads complete
#pragma unroll
    for (int tm = 0; tm < 4; tm++) {
      int nlb = wm * 64 + tm * 16 + quad * 4;      // nl = nlb + rr
      int tl = (nlb >> 6) & 1, nnb = nlb & 63;
      int kc4 = nnb >> 5;
      int qd = (nnb >> 2) & 3;
      int jb = (nnb >> 4) & 1;                     // jj = rr | (jb<<2)
#pragma unroll
      for (int tn = 0; tn < 4; tn++) {
        int gnl = wn * 64 + tn * 16 + lm;
        int hl = gnl >> 6, d = gnl & 63;
        int inner0 = (qd * 16 + (d & 15)) * 32 + (d >> 4) * 8 + jb * 4;
        unsigned int u0 = __float_as_uint(acc[tm][tn][0]) + 0x8000u;
        unsigned int u1 = __float_as_uint(acc[tm][tn][1]) + 0x8000u;
        unsigned int u2 = __float_as_uint(acc[tm][tn][2]) + 0x8000u;
        unsigned int u3 = __float_as_uint(acc[tm][tn][3]) + 0x8000u;
        uint2 pk;
        pk.x = __builtin_amdgcn_perm(u1, u0, 0x07060302u);
        pk.y = __builtin_amdgcn_perm(u3, u2, 0x07060302u);
        *(uint2*)&sm[(((hl * 2 + tl) * 2 + kc4) * 2048) + inner0] = pk;
      }
    }
    __syncthreads();
    {
      const int b = bm0 >> 11, t0 = (bm0 & 2047) >> 6, hd0 = bn0 >> 6;
#pragma unroll
      for (int c = 0; c < 8; c++) {
        int lin = (c * 256 + tid) * 8;
        int page = lin >> 11;
        int hl = page >> 2, tl = (page >> 1) & 1, kc4 = page & 1;
        int inner = lin & 2047;
        size_t idx = ((size_t)(((b << 4) + hd0 + hl) * 32 + t0 + tl) * 2 + kc4) * 2048
                   + (size_t)inner;
        *(bhalf8*)(vtl + idx) = *(const bhalf8*)(sm + lin);
      }
    }
  }
}

// ---------------------------------------------------------------------------
// Gate MLP via fp16 MFMA. 256 rows/block (4 waves x 4 tiles of 16 rows).
// h = gelu(q @ wg1^T)  [LDS C->A round-trip]  t = h @ wg2^T,
// qs = q * base * (1+tanh(t)) * (1/8)*log2(e), fp16.
// ---------------------------------------------------------------------------
__global__ __launch_bounds__(256) void k_gate(const half_t* __restrict__ qp,
                                              const float* __restrict__ base_v,
                                              const float* __restrict__ wg1,
                                              const float* __restrict__ wg2,
                                              half_t* __restrict__ qs) {
  __shared__ __align__(16) half_t W1[64 * 72];
  __shared__ __align__(16) half_t W2[64 * 72];
  __shared__ __align__(16) half_t HT[4][16 * 72];
  const int tid = threadIdx.x, lane = tid & 63, w = tid >> 6;
  const int quad = lane >> 4, lm = lane & 15;
  for (int i = tid; i < 4096; i += 256) {
    int j = i >> 6, d = i & 63;
    W1[j * 72 + d] = (half_t)wg1[i];
    W2[j * 72 + d] = (half_t)wg2[i];
  }
  __syncthreads();
  const int R0 = blockIdx.x * 256;
  const int hd = (R0 >> 11) & 15;
  float bsev[4];
#pragma unroll
  for (int tn = 0; tn < 4; tn++) bsev[tn] = base_v[hd * 64 + tn * 16 + lm];
  const float cs = 0.18033688011112042f;       // (1/8)*log2(e)
  const floatx4 zero4 = {0.f, 0.f, 0.f, 0.f};
  half_t* ht = HT[w];

  for (int ti = 0; ti < 4; ti++) {
    int r0 = R0 + w * 64 + ti * 16;
    half8 aq0 = *(const half8*)&qp[(size_t)(r0 + lm) * 64 + quad * 8];
    half8 aq1 = *(const half8*)&qp[(size_t)(r0 + lm) * 64 + 32 + quad * 8];
    floatx4 hc[4];
#pragma unroll
    for (int tn = 0; tn < 4; tn++) {
      half8 b0 = *(const half8*)&W1[(tn * 16 + lm) * 72 + quad * 8];
      half8 b1 = *(const half8*)&W1[(tn * 16 + lm) * 72 + 32 + quad * 8];
      floatx4 t = zero4;
      t = MFMAF16(aq0, b0, t);
      t = MFMAF16(aq1, b1, t);
      hc[tn] = t;
    }
#pragma unroll
    for (int tn = 0; tn < 4; tn++)
#pragma unroll
      for (int rr = 0; rr < 4; rr++)
        ht[(quad * 4 + rr) * 72 + tn * 16 + lm] = (half_t)gelu_f(hc[tn][rr]);
    // layer 2 (A-frags from per-wave LDS; in-order LDS per wave)
    half8 ah0 = *(const half8*)&ht[lm * 72 + quad * 8];
    half8 ah1 = *(const half8*)&ht[lm * 72 + 32 + quad * 8];
#pragma unroll
    for (int tn = 0; tn < 4; tn++) {
      half8 b0 = *(const half8*)&W2[(tn * 16 + lm) * 72 + quad * 8];
      half8 b1 = *(const half8*)&W2[(tn * 16 + lm) * 72 + 32 + quad * 8];
      floatx4 t = zero4;
      t = MFMAF16(ah0, b0, t);
      t = MFMAF16(ah1, b1, t);
#pragma unroll
      for (int rr = 0; rr < 4; rr++) {
        int row = r0 + quad * 4 + rr;
        int d = tn * 16 + lm;
        float qv = (float)qp[(size_t)row * 64 + d];
        float g = 1.0f + tanhf(t[rr]);
        qs[(size_t)row * 64 + d] = (half_t)(qv * bsev[tn] * g * cs);
      }
    }
  }
}

// ---------------------------------------------------------------------------
// Flash attention, deferred softmax, swapped QK^T, fully in-register,
// BARRIER-FREE (no LDS). Grid (16 hd, 8 qg x 2 half, 2 b) = 512 blocks x
// 256 thr -> 2 blocks/CU; same-head blocks pinned to one XCD.
// Each block: 256 q-rows x 1024 keys (16 tiles of 64); 64 q-rows/wave.
// K global->reg from kswz (lane-only addresses; all waves read identical
// fragments; L2-resident), register-double-buffered one tile ahead
// (kfA/kfB, unroll-2 loop). V global->reg per tile (fragment-linear vtl).
// s = mfma(K,Q): lane holds P[q=lm][k=quad*4+rr+16kb]; PV k-axis permuted
// so cvt_pk-packed exp2 results feed MFMABF16 A directly. rsum via
// ones-MFMA. No __syncthreads anywhere: waves free-run.
// ---------------------------------------------------------------------------
__global__ __launch_bounds__(256, 2) void k_attn(const half_t* __restrict__ qs,
                                                 const half_t* __restrict__ kswz,
                                                 const unsigned short* __restrict__ vtl,
                                                 unsigned short* __restrict__ Opart,
                                                 float* __restrict__ rpart) {
  const int tid = threadIdx.x;
  const int lane = tid & 63;
  const int w = tid >> 6;            // 0..3
  const int quad = lane >> 4;
  const int lm = lane & 15;
  const int a7 = lm & 7;
  const int hd = blockIdx.x;
  const int qg = blockIdx.y >> 1, half = blockIdx.y & 1;
  const int b = blockIdx.z;
  const int bh = b * 16 + hd;
  const size_t hb = (size_t)bh * 2048 * 64;
  const char* khT = (const char*)(kswz + hb) + (size_t)half * 16 * 8192;
  const unsigned short* vtT = vtl + (size_t)bh * 32 * 4096;

  half8 qh[4][2];
#pragma unroll
  for (int rg = 0; rg < 4; rg++)
#pragma unroll
    for (int kc = 0; kc < 2; kc++)
      qh[rg][kc] = *(const half8*)(qs + hb
          + (size_t)(qg * 256 + w * 64 + rg * 16 + lm) * 64 + kc * 32 + quad * 8);

  const floatx4 zero4 = {0.f, 0.f, 0.f, 0.f};
  floatx4 O[4][4];
#pragma unroll
  for (int rg = 0; rg < 4; rg++)
#pragma unroll
    for (int dt = 0; dt < 4; dt++) O[rg][dt] = zero4;
  floatx4 racc[4];                   // rsum accumulators (ones-MFMA)
#pragma unroll
  for (int rg = 0; rg < 4; rg++) racc[rg] = zero4;
  const short one_bf = (short)0x3F80;           // bf16 1.0
  const bhalf8 vones = {one_bf, one_bf, one_bf, one_bf,
                        one_bf, one_bf, one_bf, one_bf};

  // per-lane K-fragment byte offsets within a tile (same data the old LDS
  // path read: row kb*16+lm, 16B chunk (kc*4+quad)^a7)
  int koff[4][2];
#pragma unroll
  for (int kb = 0; kb < 4; kb++)
#pragma unroll
    for (int kc = 0; kc < 2; kc++)
      koff[kb][kc] = ((kb * 16 + lm) * 64 + (((kc * 4 + quad) ^ a7) << 3)) * 2;

#define LOADK(DST, T)                                                          \
  _Pragma("unroll")                                                            \
  for (int kb = 0; kb < 4; kb++)                                               \
    _Pragma("unroll")                                                          \
    for (int kc = 0; kc < 2; kc++)                                             \
      DST[kb * 2 + kc] =                                                       \
          *(const half8*)(khT + (size_t)(T) * 8192 + koff[kb][kc]);

#define LOADV(DST, T)                                                          \
  {                                                                            \
    const unsigned short* vb =                                                 \
        vtT + ((size_t)(half * 16 + (T)) * 2) * 2048 + lane * 32;              \
    _Pragma("unroll")                                                          \
    for (int kc4 = 0; kc4 < 2; kc4++)                                          \
      _Pragma("unroll")                                                        \
      for (int dt = 0; dt < 4; dt++)                                           \
        DST[kc4][dt] = *(const bhalf8*)(vb + kc4 * 2048 + dt * 8);             \
  }

#define TILE_COMPUTE(KF, VF)                                                   \
  {                                                                            \
    _Pragma("unroll")                                                          \
    for (int p = 0; p < 2; p++) {                                              \
      floatx4 s[2][4];                                                         \
      _Pragma("unroll")                                                        \
      for (int ri = 0; ri < 2; ri++)                                           \
        _Pragma("unroll")                                                      \
        for (int kb = 0; kb < 4; kb++) s[ri][kb] = zero4;                      \
      __builtin_amdgcn_s_setprio(1);                                           \
      _Pragma("unroll")                                                        \
      for (int kb = 0; kb < 4; kb++)                                           \
        _Pragma("unroll")                                                      \
        for (int kc = 0; kc < 2; kc++) {                                       \
          half8 khf = KF[kb * 2 + kc];                                         \
          _Pragma("unroll")                                                    \
          for (int ri = 0; ri < 2; ri++)                                       \
            s[ri][kb] = MFMAF16(khf, qh[p * 2 + ri][kc], s[ri][kb]);           \
        }                                                                      \
      __builtin_amdgcn_s_setprio(0);                                           \
      _Pragma("unroll")                                                        \
      for (int ri = 0; ri < 2; ri++) {                                         \
        const int rg = p * 2 + ri;                                             \
        float e[4][4];                                                         \
        _Pragma("unroll")                                                      \
        for (int kb = 0; kb < 4; kb++)                                         \
          _Pragma("unroll")                                                    \
          for (int rr = 0; rr < 4; rr++)                                       \
            e[kb][rr] = __builtin_amdgcn_exp2f(s[ri][kb][rr]);                 \
        __builtin_amdgcn_s_setprio(1);                                         \
        _Pragma("unroll")                                                      \
        for (int kc4 = 0; kc4 < 2; kc4++) {                                    \
          union { unsigned int w4[4]; bhalf8 v; } pa;                          \
          pa.w4[0] = cvtpk_bf16(e[2 * kc4][0],     e[2 * kc4][1]);             \
          pa.w4[1] = cvtpk_bf16(e[2 * kc4][2],     e[2 * kc4][3]);             \
          pa.w4[2] = cvtpk_bf16(e[2 * kc4 + 1][0], e[2 * kc4 + 1][1]);         \
          pa.w4[3] = cvtpk_bf16(e[2 * kc4 + 1][2], e[2 * kc4 + 1][3]);         \
          racc[rg] = MFMABF16(pa.v, vones, racc[rg]);                          \
          _Pragma("unroll")                                                    \
          for (int dt = 0; dt < 4; dt++)                                       \
            O[rg][dt] = MFMABF16(pa.v, VF[kc4][dt], O[rg][dt]);                \
        }                                                                      \
        __builtin_amdgcn_s_setprio(0);                                         \
      }                                                                        \
    }                                                                          \
  }

  half8 kfA[8], kfB[8];
  LOADK(kfA, 0);                               // prefetch tile 0
  for (int t = 0; t < 16; t += 2) {
    bhalf8 vf[2][4];
    LOADV(vf, t);
    LOADK(kfB, t + 1);                         // prefetch tile t+1
    TILE_COMPUTE(kfA, vf);                     // compute tile t
    LOADV(vf, t + 1);
    if (t < 14) LOADK(kfA, t + 2);             // prefetch tile t+2
    TILE_COMPUTE(kfB, vf);                     // compute tile t+1
  }
#undef LOADK
#undef LOADV
#undef TILE_COMPUTE

  // epilogue: rsum direct from racc (row = quad*4+rr, same as O) and
  // bf16 O-partials
  unsigned short* op = Opart + (size_t)half * 65536 * 64;
  float* rp = rpart + (size_t)half * 65536;
#pragma unroll
  for (int rg = 0; rg < 4; rg++) {
#pragma unroll
    for (int rr = 0; rr < 4; rr++) {
      int n = qg * 256 + w * 64 + rg * 16 + quad * 4 + rr;
      size_t row = (size_t)bh * 2048 + n;
      if (lm == 0) rp[row] = racc[rg][rr];
#pragma unroll
      for (int dt = 0; dt < 4; dt++)
        op[row * 64 + dt * 16 + lm] = f2bf(O[rg][dt][rr]);
    }
  }
}

// ---------------------------------------------------------------------------
// combine: o = (O0+O1)/(r0+r1) -> obf fp16 [4096,1024] (out-proj A layout)
// ---------------------------------------------------------------------------
__global__ __launch_bounds__(256) void k_combine(const unsigned short* __restrict__ Opart,
                                                 const float* __restrict__ rpart,
                                                 half_t* __restrict__ obf) {
  size_t e = ((size_t)blockIdx.x * 256 + threadIdx.x) * 8;
  size_t row = e >> 6; int d0 = (int)(e & 63);
  float inv = 1.0f / (rpart[row] + rpart[65536 + row]);
  bhalf8 o0 = *(const bhalf8*)&Opart[row * 64 + d0];
  bhalf8 o1 = *(const bhalf8*)&Opart[(size_t)65536 * 64 + row * 64 + d0];
  int b = (int)(row >> 15), h = (int)((row >> 11) & 15), n = (int)(row & 2047);
  half8 o;
#pragma unroll
  for (int j = 0; j < 8; j++)
    o[j] = (half_t)((bf2f((unsigned short)o0[j]) + bf2f((unsigned short)o1[j])) * inv);
  *(half8*)&obf[((size_t)(b * 2048 + n)) * 1024 + h * 64 + d0] = o;
}

// ---------------------------------------------------------------------------
extern "C" void kernel_launch(void* const* d_in, const int* in_sizes, int n_in,
                              void* d_out, int out_size, void* d_ws, size_t ws_size,
                              hipStream_t stream) {
  const float* query = (const float*)d_in[0];
  const float* key_  = (const float*)d_in[1];
  const float* value = (const float*)d_in[2];
  const float* wq  = (const float*)d_in[4];
  const float* wk  = (const float*)d_in[5];
  const float* wv  = (const float*)d_in[6];
  const float* wo  = (const float*)d_in[7];
  const float* wb1 = (const float*)d_in[8];
  const float* wb2 = (const float*)d_in[9];
  const float* wg1 = (const float*)d_in[10];
  const float* wg2 = (const float*)d_in[11];
  const int* nctx  = (const int*)d_in[12];
  float* out = (float*)d_out;

  char* ws = (char*)d_ws;
  size_t o = 0;
  float* base_v = (float*)(ws + o); o += 4096;
  half_t* q16   = (half_t*)(ws + o); o += (size_t)4096 * 1024 * 2;   // later: qs
  half_t* k16   = (half_t*)(ws + o); o += (size_t)4096 * 1024 * 2;   // later: obf
  half_t* v16   = (half_t*)(ws + o); o += (size_t)4096 * 1024 * 2;
  half_t* w16   = (half_t*)(ws + o); o += (size_t)4 * 1024 * 1024 * 2;
  half_t* qp16  = (half_t*)(ws + o); o += (size_t)4096 * 1024 * 2;
  half_t* kswz  = (half_t*)(ws + o); o += (size_t)4096 * 1024 * 2;
  unsigned short* vtl = (unsigned short*)(ws + o); o += (size_t)4096 * 1024 * 2;
  unsigned short* Opart = (unsigned short*)(ws + o); o += (size_t)2 * 65536 * 64 * 2;
  float* rpart = (float*)(ws + o); o += (size_t)2 * 65536 * 4;
  half_t* qs  = q16;    // aliases (q16/k16 dead after k_gemm<0>)
  half_t* obf = k16;

  k_cvtbase<<<8196, 256, 0, stream>>>(query, key_, value, wq, wk, wv, wo,
                                      q16, k16, v16, w16, wb1, wb2, nctx, base_v);
  k_gemm<0><<<dim3(8, 32, 3), 256, 0, stream>>>(q16, w16, qp16, kswz, vtl, nullptr);
  k_gate<<<256, 256, 0, stream>>>(qp16, base_v, wg1, wg2, qs);
  k_attn<<<dim3(16, 16, 2), 256, 0, stream>>>(qs, kswz, vtl, Opart, rpart);
  k_combine<<<2048, 256, 0, stream>>>(Opart, rpart, obf);
  k_gemm<3><<<dim3(8, 32, 1), 256, 0, stream>>>(obf, w16 + (size_t)3 * 1048576,
                                                nullptr, nullptr, nullptr, out);
}

// Round 12
// 265.872 us; speedup vs baseline: 1.2020x; 1.2020x over previous
//
#include <hip/hip_runtime.h>
#include <math.h>

// ---------------------------------------------------------------------------
// QASS Multihead Attention, MI355X (gfx950)
// B=2, N=2048, D=1024, H=16, Dh=64, HID=64. Output fp32 [B,N,D].
//
// R17: (1) REVERT R16's barrier-free attn (it spilled: 164 VGPR demand vs
//      128 cap -> 297MB scratch writes, 42.5 -> 115us). k_attn = R15's
//      LDS-staged version (proven 42.5us).
//      (2) k_combine FUSED into k_gemm<3>'s A-staging: MODE 3 reg-stages
//      A = (O0+O1)/(r0+r1) from Opart/rpart (loads issued at step top,
//      latency hides under current tile's MFMA; convert + ds_write late,
//      exact dma16 lane->slot mapping). Deletes the combine kernel + obf
//      round-trip (one less launch + gap).
// Precision: fp16 projections/QK^T, bf16 P*V and O-partials, fp32 softmax
// (deferred, log2 domain; exp2 never overflows fp32).
// ---------------------------------------------------------------------------

typedef _Float16 half_t;
using half8   = __attribute__((ext_vector_type(8))) _Float16;  // 4 VGPRs
using bhalf8  = __attribute__((ext_vector_type(8))) short;     // 8 bf16
using floatx4 = __attribute__((ext_vector_type(4))) float;     // MFMA C/D

__device__ inline unsigned short f2bf(float f) {
  union { float f; unsigned int u; } v; v.f = f;
  unsigned int u = v.u;
  u = u + 0x7fffu + ((u >> 16) & 1u);
  return (unsigned short)(u >> 16);
}
__device__ inline float bf2f(unsigned short h) {
  union { unsigned int u; float f; } v; v.u = ((unsigned int)h) << 16;
  return v.f;
}
__device__ inline float gelu_f(float x) {      // exact (erf) GELU
  return 0.5f * x * (1.0f + erff(x * 0.70710678118654752440f));
}
__device__ __forceinline__ unsigned int cvtpk_bf16(float lo, float hi) {
  unsigned int r;
  asm("v_cvt_pk_bf16_f32 %0, %1, %2" : "=v"(r) : "v"(lo), "v"(hi));
  return r;
}

#define MFMAF16(a, b, c)  __builtin_amdgcn_mfma_f32_16x16x32_f16((a), (b), (c), 0, 0, 0)
#define MFMABF16(a, b, c) __builtin_amdgcn_mfma_f32_16x16x32_bf16((a), (b), (c), 0, 0, 0)

__device__ __forceinline__ void dma16(const void* g, void* l) {
  __builtin_amdgcn_global_load_lds(
      (const __attribute__((address_space(1))) unsigned int*)g,
      (__attribute__((address_space(3))) unsigned int*)l, 16, 0, 0);
}

// ---------------------------------------------------------------------------
// fp32->fp16 conversion (q/k/v 3x4M + weights 4x1M) and (blocks >= 8192)
// base[1024] = gelu(log(n) * wb1) @ wb2.T
// ---------------------------------------------------------------------------
__global__ __launch_bounds__(256) void k_cvtbase(
    const float* __restrict__ q, const float* __restrict__ k, const float* __restrict__ v,
    const float* __restrict__ wq, const float* __restrict__ wk,
    const float* __restrict__ wv, const float* __restrict__ wo,
    half_t* __restrict__ q16, half_t* __restrict__ k16, half_t* __restrict__ v16,
    half_t* __restrict__ w16,
    const float* __restrict__ wb1, const float* __restrict__ wb2,
    const int* __restrict__ nctx, float* __restrict__ base_out) {
  int tid = threadIdx.x;
  if (blockIdx.x >= 8192) {                    // base path (4 blocks)
    __shared__ float h1[64];
    float logn = logf((float)(*nctx));
    if (tid < 64) h1[tid] = gelu_f(logn * wb1[tid]);
    __syncthreads();
    int i = (blockIdx.x - 8192) * 256 + tid;
    float s = 0.f;
#pragma unroll
    for (int j = 0; j < 64; j++) s += h1[j] * wb2[i * 64 + j];
    base_out[i] = s;
    return;
  }
  size_t e = ((size_t)blockIdx.x * 256 + tid) * 8;
  const float* src; half_t* dst; size_t off;
  if (e < (size_t)3 * 4194304) {
    int t = (int)(e >> 22); off = e & 4194303;
    src = (t == 0) ? q : (t == 1 ? k : v);
    dst = (t == 0) ? q16 : (t == 1 ? k16 : v16);
  } else {
    size_t e2 = e - (size_t)3 * 4194304;
    int t = (int)(e2 >> 20); off = (e2 & 1048575);
    src = (t == 0) ? wq : (t == 1 ? wk : (t == 2 ? wv : wo));
    dst = w16 + (size_t)t * 1048576;
  }
  float4 a = *(const float4*)(src + off);
  float4 b = *(const float4*)(src + off + 4);
  half8 h;
  h[0] = (half_t)a.x; h[1] = (half_t)a.y; h[2] = (half_t)a.z; h[3] = (half_t)a.w;
  h[4] = (half_t)b.x; h[5] = (half_t)b.y; h[6] = (half_t)b.z; h[7] = (half_t)b.w;
  *(half8*)(dst + off) = h;
}

// ---------------------------------------------------------------------------
// fp16 GEMM  C[4096,1024] = A @ W^T, 128x128 tile, BK=32, 4 waves (2x2),
// each wave 64x64 (4x4 frags). BK=32 double-buffered staging (2x16KB=32KB):
// per step {barrier; issue next-step staging; compute buf}. MODE 0 stages A
// via dma16; MODE 3 reg-stages A = (O0+O1)/(r0+r1) from Opart/rpart
// (combine fused; loads issued early, ds_write after compute -- T14).
// After the K-loop the 32KB LDS is reused as an epilogue transpose buffer
// for z=1/z=2 (output-linear staging, then 8x coalesced 16B stores/thread).
// MODE 0 (QKV, grid.z selects): z=0 -> qp16 [B,H,N,Dh] fp16 (direct)
//                               z=1 -> kswz fp16 (chunk-swizzled d)
//                               z=2 -> vtl bf16, fragment-linear per tile
//   for the k-permuted PV: key nn (in tile) decomposes kc4=nn>>5,
//   quad=(nn>>2)&3, j=(nn&3)|(((nn>>4)&1)<<2); cell [kc4][lane=quad*16+lm]
//   [dt][j] holds V[key][d=dt*16+lm] (64B/lane contiguous per kc4).
// MODE 3: Abase=(half_t*)Opart, vtl=(unsigned short*)rpart -> fp32 out.
// ---------------------------------------------------------------------------
template <int MODE>
__global__ __launch_bounds__(256, 3) void k_gemm(const half_t* __restrict__ Abase,
                                                 const half_t* __restrict__ Wbase,
                                                 half_t* __restrict__ qp16,
                                                 half_t* __restrict__ kswz,
                                                 unsigned short* __restrict__ vtl,
                                                 float* __restrict__ outf) {
  const int z = (MODE == 0) ? blockIdx.z : 0;
  const half_t* Ag = Abase + (size_t)z * 4194304;
  const half_t* Wg = Wbase + (size_t)z * 1048576;
  const unsigned short* OP = (const unsigned short*)Abase;   // MODE 3
  const float* rp = (const float*)vtl;                       // MODE 3
  __shared__ __align__(16) half_t SM[4][128 * 32];   // A0,A1,B0,B1; 32 KB
  const int tid = threadIdx.x, lane = tid & 63, w = tid >> 6;
  const int quad = lane >> 4, lm = lane & 15;
  const int wm = w >> 1, wn = w & 1;
  const int bm0 = blockIdx.y * 128, bn0 = blockIdx.x * 128;

  const floatx4 zero4 = {0.f, 0.f, 0.f, 0.f};
  floatx4 acc[4][4];
#pragma unroll
  for (int i = 0; i < 4; i++)
#pragma unroll
    for (int j = 0; j < 4; j++) acc[i][j] = zero4;

  // staging constants (lane-only; bijective per 16-row group)
  const int j4 = lane >> 2;                              // 0..15
  const int cs = (lane & 3) ^ (((j4 & 3) + (j4 >> 2)) & 3);
  const int ub = ((lm & 3) + (lm >> 2)) & 3;             // read-side XOR

  // prologue: stage kk=0 -> buf 0
#pragma unroll
  for (int i = 0; i < 2; i++) {
    int tr = w * 32 + i * 16 + j4;
    if constexpr (MODE == 3) {
      int gm = bm0 + tr;
      int bb = gm >> 11, n = gm & 2047;
      int col = cs * 8;                        // kk = 0
      int h = col >> 6, d0 = col & 63;
      size_t prow = (size_t)(bb * 16 + h) * 2048 + n;
      float inv = 1.0f / (rp[prow] + rp[65536 + prow]);
      bhalf8 a0 = *(const bhalf8*)(OP + prow * 64 + d0);
      bhalf8 a1 = *(const bhalf8*)(OP + (size_t)65536 * 64 + prow * 64 + d0);
      half8 hv;
#pragma unroll
      for (int jj = 0; jj < 8; jj++)
        hv[jj] = (half_t)((bf2f((unsigned short)a0[jj])
                         + bf2f((unsigned short)a1[jj])) * inv);
      *(half8*)((char*)SM[0] + (w * 32 + i * 16) * 64 + lane * 16) = hv;
    } else {
      dma16((const char*)Ag + ((size_t)(bm0 + tr) * 1024 + cs * 8) * 2,
            (char*)SM[0] + (w * 32 + i * 16) * 64);
    }
    dma16((const char*)Wg + ((size_t)(bn0 + tr) * 1024 + cs * 8) * 2,
          (char*)SM[2] + (w * 32 + i * 16) * 64);
  }

  for (int kk = 0; kk < 1024; kk += 32) {
    const int cur = (kk >> 5) & 1;
    __syncthreads();                 // drains staging for buf[cur]
    const bool pf = kk < 992;

    bhalf8 a0v[2], a1v[2];
    float invv[2];
    if (pf) {
#pragma unroll
      for (int i = 0; i < 2; i++) {
        int tr = w * 32 + i * 16 + j4;
        if constexpr (MODE == 3) {
          int gm = bm0 + tr;
          int bb = gm >> 11, n = gm & 2047;
          int col = kk + 32 + cs * 8;
          int h = col >> 6, d0 = col & 63;
          size_t prow = (size_t)(bb * 16 + h) * 2048 + n;
          invv[i] = 1.0f / (rp[prow] + rp[65536 + prow]);
          a0v[i] = *(const bhalf8*)(OP + prow * 64 + d0);
          a1v[i] = *(const bhalf8*)(OP + (size_t)65536 * 64 + prow * 64 + d0);
        } else {
          dma16((const char*)Ag + ((size_t)(bm0 + tr) * 1024 + kk + 32 + cs * 8) * 2,
                (char*)SM[cur ^ 1] + (w * 32 + i * 16) * 64);
        }
        dma16((const char*)Wg + ((size_t)(bn0 + tr) * 1024 + kk + 32 + cs * 8) * 2,
              (char*)SM[2 + (cur ^ 1)] + (w * 32 + i * 16) * 64);
      }
    }

    const half_t* as_ = SM[cur];
    const half_t* bs_ = SM[2 + cur];
    half8 af[4], bf[4];
#pragma unroll
    for (int tm = 0; tm < 4; tm++)
      af[tm] = *(const half8*)&as_[(wm * 64 + tm * 16 + lm) * 32
                                   + ((quad ^ ub) << 3)];
#pragma unroll
    for (int tn = 0; tn < 4; tn++)
      bf[tn] = *(const half8*)&bs_[(wn * 64 + tn * 16 + lm) * 32
                                   + ((quad ^ ub) << 3)];
#pragma unroll
    for (int tm = 0; tm < 4; tm++)
#pragma unroll
      for (int tn = 0; tn < 4; tn++)
        acc[tm][tn] = MFMAF16(af[tm], bf[tn], acc[tm][tn]);

    if constexpr (MODE == 3) {
      if (pf) {                      // write-late: loads returned under MFMA
#pragma unroll
        for (int i = 0; i < 2; i++) {
          half8 hv;
#pragma unroll
          for (int jj = 0; jj < 8; jj++)
            hv[jj] = (half_t)((bf2f((unsigned short)a0v[i][jj])
                             + bf2f((unsigned short)a1v[i][jj])) * invv[i]);
          *(half8*)((char*)SM[cur ^ 1] + (w * 32 + i * 16) * 64 + lane * 16) = hv;
        }
      }
    }
  }

  // ---- epilogue ----
  if constexpr (MODE == 3) {
#pragma unroll
    for (int tm = 0; tm < 4; tm++)
#pragma unroll
      for (int tn = 0; tn < 4; tn++)
#pragma unroll
        for (int rr = 0; rr < 4; rr++) {
          int gm = bm0 + wm * 64 + tm * 16 + quad * 4 + rr;
          int gn = bn0 + wn * 64 + tn * 16 + lm;
          outf[(size_t)gm * 1024 + gn] = acc[tm][tn][rr];
        }
  } else if (z == 0) {
    // direct fp16 stores (per-instruction footprint: 4 x 32B lines -- ok)
#pragma unroll
    for (int tm = 0; tm < 4; tm++)
#pragma unroll
      for (int tn = 0; tn < 4; tn++)
#pragma unroll
        for (int rr = 0; rr < 4; rr++) {
          int gm = bm0 + wm * 64 + tm * 16 + quad * 4 + rr;   // b*2048+n
          int gn = bn0 + wn * 64 + tn * 16 + lm;              // h*64+d
          int b = gm >> 11, n = gm & 2047, hd = gn >> 6, d = gn & 63;
          qp16[((size_t)((b << 4) + hd) * 2048 + n) * 64 + d] = (half_t)acc[tm][tn][rr];
        }
  } else if (z == 1) {
    // LDS-staged: sm[(hl*128+nl)*64 + swz] then linear 16B writes
    half_t* smh = (half_t*)&SM[0][0];
    __syncthreads();                 // K-loop LDS reads complete
#pragma unroll
    for (int tm = 0; tm < 4; tm++)
#pragma unroll
      for (int tn = 0; tn < 4; tn++) {
        int gnl = wn * 64 + tn * 16 + lm;          // local gn 0..127
        int hl = gnl >> 6, d = gnl & 63;
#pragma unroll
        for (int rr = 0; rr < 4; rr++) {
          int nl = wm * 64 + tm * 16 + quad * 4 + rr;
          int sw = ((((d >> 3) ^ (nl & 7)) << 3) | (d & 7));
          smh[(hl * 128 + nl) * 64 + sw] = (half_t)acc[tm][tn][rr];
        }
      }
    __syncthreads();
    {
      const int b = bm0 >> 11, n0 = bm0 & 2047, hd0 = bn0 >> 6;
#pragma unroll
      for (int c = 0; c < 8; c++) {
        int lin = (c * 256 + tid) * 8;
        int hl = lin >> 13, nl = (lin >> 6) & 127, j0 = lin & 63;
        size_t row = (size_t)((b << 4) + hd0 + hl) * 2048 + n0 + nl;
        *(half8*)(kswz + row * 64 + j0) = *(const half8*)(smh + lin);
      }
    }
  } else {
    // z == 2: LDS-staged, rr-packed 8B writes, then linear 16B writes
    unsigned short* sm = (unsigned short*)&SM[0][0];
    __syncthreads();                 // K-loop LDS reads complete
#pragma unroll
    for (int tm = 0; tm < 4; tm++) {
      int nlb = wm * 64 + tm * 16 + quad * 4;      // nl = nlb + rr
      int tl = (nlb >> 6) & 1, nnb = nlb & 63;
      int kc4 = nnb >> 5;
      int qd = (nnb >> 2) & 3;
      int jb = (nnb >> 4) & 1;                     // jj = rr | (jb<<2)
#pragma unroll
      for (int tn = 0; tn < 4; tn++) {
        int gnl = wn * 64 + tn * 16 + lm;
        int hl = gnl >> 6, d = gnl & 63;
        int inner0 = (qd * 16 + (d & 15)) * 32 + (d >> 4) * 8 + jb * 4;
        unsigned int u0 = __float_as_uint(acc[tm][tn][0]) + 0x8000u;
        unsigned int u1 = __float_as_uint(acc[tm][tn][1]) + 0x8000u;
        unsigned int u2 = __float_as_uint(acc[tm][tn][2]) + 0x8000u;
        unsigned int u3 = __float_as_uint(acc[tm][tn][3]) + 0x8000u;
        uint2 pk;
        pk.x = __builtin_amdgcn_perm(u1, u0, 0x07060302u);
        pk.y = __builtin_amdgcn_perm(u3, u2, 0x07060302u);
        *(uint2*)&sm[(((hl * 2 + tl) * 2 + kc4) * 2048) + inner0] = pk;
      }
    }
    __syncthreads();
    {
      const int b = bm0 >> 11, t0 = (bm0 & 2047) >> 6, hd0 = bn0 >> 6;
#pragma unroll
      for (int c = 0; c < 8; c++) {
        int lin = (c * 256 + tid) * 8;
        int page = lin >> 11;
        int hl = page >> 2, tl = (page >> 1) & 1, kc4 = page & 1;
        int inner = lin & 2047;
        size_t idx = ((size_t)(((b << 4) + hd0 + hl) * 32 + t0 + tl) * 2 + kc4) * 2048
                   + (size_t)inner;
        *(bhalf8*)(vtl + idx) = *(const bhalf8*)(sm + lin);
      }
    }
  }
}

// ---------------------------------------------------------------------------
// Gate MLP via fp16 MFMA. 256 rows/block (4 waves x 4 tiles of 16 rows).
// h = gelu(q @ wg1^T)  [LDS C->A round-trip]  t = h @ wg2^T,
// qs = q * base * (1+tanh(t)) * (1/8)*log2(e), fp16.
// ---------------------------------------------------------------------------
__global__ __launch_bounds__(256) void k_gate(const half_t* __restrict__ qp,
                                              const float* __restrict__ base_v,
                                              const float* __restrict__ wg1,
                                              const float* __restrict__ wg2,
                                              half_t* __restrict__ qs) {
  __shared__ __align__(16) half_t W1[64 * 72];
  __shared__ __align__(16) half_t W2[64 * 72];
  __shared__ __align__(16) half_t HT[4][16 * 72];
  const int tid = threadIdx.x, lane = tid & 63, w = tid >> 6;
  const int quad = lane >> 4, lm = lane & 15;
  for (int i = tid; i < 4096; i += 256) {
    int j = i >> 6, d = i & 63;
    W1[j * 72 + d] = (half_t)wg1[i];
    W2[j * 72 + d] = (half_t)wg2[i];
  }
  __syncthreads();
  const int R0 = blockIdx.x * 256;
  const int hd = (R0 >> 11) & 15;
  float bsev[4];
#pragma unroll
  for (int tn = 0; tn < 4; tn++) bsev[tn] = base_v[hd * 64 + tn * 16 + lm];
  const float cs = 0.18033688011112042f;       // (1/8)*log2(e)
  const floatx4 zero4 = {0.f, 0.f, 0.f, 0.f};
  half_t* ht = HT[w];

  for (int ti = 0; ti < 4; ti++) {
    int r0 = R0 + w * 64 + ti * 16;
    half8 aq0 = *(const half8*)&qp[(size_t)(r0 + lm) * 64 + quad * 8];
    half8 aq1 = *(const half8*)&qp[(size_t)(r0 + lm) * 64 + 32 + quad * 8];
    floatx4 hc[4];
#pragma unroll
    for (int tn = 0; tn < 4; tn++) {
      half8 b0 = *(const half8*)&W1[(tn * 16 + lm) * 72 + quad * 8];
      half8 b1 = *(const half8*)&W1[(tn * 16 + lm) * 72 + 32 + quad * 8];
      floatx4 t = zero4;
      t = MFMAF16(aq0, b0, t);
      t = MFMAF16(aq1, b1, t);
      hc[tn] = t;
    }
#pragma unroll
    for (int tn = 0; tn < 4; tn++)
#pragma unroll
      for (int rr = 0; rr < 4; rr++)
        ht[(quad * 4 + rr) * 72 + tn * 16 + lm] = (half_t)gelu_f(hc[tn][rr]);
    // layer 2 (A-frags from per-wave LDS; in-order LDS per wave)
    half8 ah0 = *(const half8*)&ht[lm * 72 + quad * 8];
    half8 ah1 = *(const half8*)&ht[lm * 72 + 32 + quad * 8];
#pragma unroll
    for (int tn = 0; tn < 4; tn++) {
      half8 b0 = *(const half8*)&W2[(tn * 16 + lm) * 72 + quad * 8];
      half8 b1 = *(const half8*)&W2[(tn * 16 + lm) * 72 + 32 + quad * 8];
      floatx4 t = zero4;
      t = MFMAF16(ah0, b0, t);
      t = MFMAF16(ah1, b1, t);
#pragma unroll
      for (int rr = 0; rr < 4; rr++) {
        int row = r0 + quad * 4 + rr;
        int d = tn * 16 + lm;
        float qv = (float)qp[(size_t)row * 64 + d];
        float g = 1.0f + tanhf(t[rr]);
        qs[(size_t)row * 64 + d] = (half_t)(qv * bsev[tn] * g * cs);
      }
    }
  }
}

// ---------------------------------------------------------------------------
// Flash attention, deferred softmax, swapped QK^T, in-register P path.
// Grid (16 hd, 8 qg x 2 half, 2 b) = 512 blocks x 256 thr -> 2 blocks/CU;
// same-head blocks pinned to one XCD. Each block: 256 q-rows x 1024 keys
// (16 tiles of 64). Per wave: 64 q-rows (4 rg, 2 pairs).
// K staged via dma16 double-buffer in LDS (only LDS user, 16 KB);
// V global->reg (fragment-linear vtl, L2-resident).
// s = mfma(K,Q): lane holds P[q=lm][k=quad*4+rr+16kb]; PV k-axis permuted
// (phys k = 32kc4+quad*4+(j&3)+16(j>>2)) so cvt_pk-packed exp2 results feed
// MFMABF16 A-fragment directly -- no LDS round-trip. rsum via ones-MFMA
// (row-sum of the same bf16 P; no VALU adds, no epilogue shuffles).
// ---------------------------------------------------------------------------
__global__ __launch_bounds__(256, 2) void k_attn(const half_t* __restrict__ qs,
                                                 const half_t* __restrict__ kswz,
                                                 const unsigned short* __restrict__ vtl,
                                                 unsigned short* __restrict__ Opart,
                                                 float* __restrict__ rpart) {
  __shared__ __align__(16) half_t KH[2][64 * 64];           // 2 x 8 KB

  const int tid = threadIdx.x;
  const int lane = tid & 63;
  const int w = tid >> 6;            // 0..3
  const int quad = lane >> 4;
  const int lm = lane & 15;
  const int a7 = lm & 7;
  const int hd = blockIdx.x;
  const int qg = blockIdx.y >> 1, half = blockIdx.y & 1;
  const int b = blockIdx.z;
  const int bh = b * 16 + hd;
  const size_t hb = (size_t)bh * 2048 * 64;
  const char* khT = (const char*)(kswz + hb);
  const unsigned short* vtT = vtl + (size_t)bh * 32 * 4096;

  half8 qh[4][2];
#pragma unroll
  for (int rg = 0; rg < 4; rg++)
#pragma unroll
    for (int kc = 0; kc < 2; kc++)
      qh[rg][kc] = *(const half8*)(qs + hb
          + (size_t)(qg * 256 + w * 64 + rg * 16 + lm) * 64 + kc * 32 + quad * 8);

  const floatx4 zero4 = {0.f, 0.f, 0.f, 0.f};
  floatx4 O[4][4];
#pragma unroll
  for (int rg = 0; rg < 4; rg++)
#pragma unroll
    for (int dt = 0; dt < 4; dt++) O[rg][dt] = zero4;
  floatx4 racc[4];                   // rsum accumulators (ones-MFMA)
#pragma unroll
  for (int rg = 0; rg < 4; rg++) racc[rg] = zero4;
  const short one_bf = (short)0x3F80;           // bf16 1.0
  const bhalf8 vones = {one_bf, one_bf, one_bf, one_bf,
                        one_bf, one_bf, one_bf, one_bf};

  const int lo16 = lane * 16;
  const size_t g0 = (size_t)half * 16 * 8192;

  // prologue: stage K tile 0 of this half (2 dma16/wave)
#pragma unroll
  for (int r = 0; r < 2; r++) {
    int sb = (w * 2 + r) * 1024;
    dma16(khT + g0 + sb + lo16, (char*)KH[0] + sb);
  }

  for (int t = 0; t < 16; t++) {
    const int cur = t & 1;
    __syncthreads();

    // V fragments global->reg (issued first; PV's vmcnt wait then leaves
    // the younger K-dma prefetch in flight)
    const unsigned short* vb = vtT + ((size_t)(half * 16 + t) * 2) * 2048 + lane * 32;
    bhalf8 vf[2][4];
#pragma unroll
    for (int kc4 = 0; kc4 < 2; kc4++)
#pragma unroll
      for (int dt = 0; dt < 4; dt++)
        vf[kc4][dt] = *(const bhalf8*)(vb + kc4 * 2048 + dt * 8);

    if (t < 15) {
      const size_t gof = g0 + (size_t)(t + 1) * 8192;
#pragma unroll
      for (int r = 0; r < 2; r++) {
        int sb = (w * 2 + r) * 1024;
        dma16(khT + gof + sb + lo16, (char*)KH[cur ^ 1] + sb);
      }
    }

    const half_t* kh_ = KH[cur];

#pragma unroll
    for (int p = 0; p < 2; p++) {
      floatx4 s[2][4];
#pragma unroll
      for (int ri = 0; ri < 2; ri++)
#pragma unroll
        for (int kb = 0; kb < 4; kb++) s[ri][kb] = zero4;

      __builtin_amdgcn_s_setprio(1);
#pragma unroll
      for (int kb = 0; kb < 4; kb++)
#pragma unroll
        for (int kc = 0; kc < 2; kc++) {
          int addr = (kb * 16 + lm) * 64 + (((kc * 4 + quad) ^ a7) << 3);
          half8 khf = *(const half8*)&kh_[addr];
          // swapped: A = K (rows=keys), B = Q (cols=q-rows)
#pragma unroll
          for (int ri = 0; ri < 2; ri++)
            s[ri][kb] = MFMAF16(khf, qh[p * 2 + ri][kc], s[ri][kb]);
        }
      __builtin_amdgcn_s_setprio(0);

#pragma unroll
      for (int ri = 0; ri < 2; ri++) {
        const int rg = p * 2 + ri;
        // exp2 of all 16 in-lane scores (q-row lm, keys quad*4+rr+16kb)
        float e[4][4];
#pragma unroll
        for (int kb = 0; kb < 4; kb++)
#pragma unroll
          for (int rr = 0; rr < 4; rr++)
            e[kb][rr] = __builtin_amdgcn_exp2f(s[ri][kb][rr]);

        __builtin_amdgcn_s_setprio(1);
#pragma unroll
        for (int kc4 = 0; kc4 < 2; kc4++) {
          union { unsigned int w4[4]; bhalf8 v; } pa;
          pa.w4[0] = cvtpk_bf16(e[2 * kc4][0],     e[2 * kc4][1]);
          pa.w4[1] = cvtpk_bf16(e[2 * kc4][2],     e[2 * kc4][3]);
          pa.w4[2] = cvtpk_bf16(e[2 * kc4 + 1][0], e[2 * kc4 + 1][1]);
          pa.w4[3] = cvtpk_bf16(e[2 * kc4 + 1][2], e[2 * kc4 + 1][3]);
          racc[rg] = MFMABF16(pa.v, vones, racc[rg]);   // row-sum of P
#pragma unroll
          for (int dt = 0; dt < 4; dt++)
            O[rg][dt] = MFMABF16(pa.v, vf[kc4][dt], O[rg][dt]);
        }
        __builtin_amdgcn_s_setprio(0);
      }
    }
  }

  // epilogue: rsum direct from racc (row = quad*4+rr, same as O) and
  // bf16 O-partials
  unsigned short* op = Opart + (size_t)half * 65536 * 64;
  float* rp = rpart + (size_t)half * 65536;
#pragma unroll
  for (int rg = 0; rg < 4; rg++) {
#pragma unroll
    for (int rr = 0; rr < 4; rr++) {
      int n = qg * 256 + w * 64 + rg * 16 + quad * 4 + rr;
      size_t row = (size_t)bh * 2048 + n;
      if (lm == 0) rp[row] = racc[rg][rr];
#pragma unroll
      for (int dt = 0; dt < 4; dt++)
        op[row * 64 + dt * 16 + lm] = f2bf(O[rg][dt][rr]);
    }
  }
}

// ---------------------------------------------------------------------------
extern "C" void kernel_launch(void* const* d_in, const int* in_sizes, int n_in,
                              void* d_out, int out_size, void* d_ws, size_t ws_size,
                              hipStream_t stream) {
  const float* query = (const float*)d_in[0];
  const float* key_  = (const float*)d_in[1];
  const float* value = (const float*)d_in[2];
  const float* wq  = (const float*)d_in[4];
  const float* wk  = (const float*)d_in[5];
  const float* wv  = (const float*)d_in[6];
  const float* wo  = (const float*)d_in[7];
  const float* wb1 = (const float*)d_in[8];
  const float* wb2 = (const float*)d_in[9];
  const float* wg1 = (const float*)d_in[10];
  const float* wg2 = (const float*)d_in[11];
  const int* nctx  = (const int*)d_in[12];
  float* out = (float*)d_out;

  char* ws = (char*)d_ws;
  size_t o = 0;
  float* base_v = (float*)(ws + o); o += 4096;
  half_t* q16   = (half_t*)(ws + o); o += (size_t)4096 * 1024 * 2;   // later: qs
  half_t* k16   = (half_t*)(ws + o); o += (size_t)4096 * 1024 * 2;
  half_t* v16   = (half_t*)(ws + o); o += (size_t)4096 * 1024 * 2;
  half_t* w16   = (half_t*)(ws + o); o += (size_t)4 * 1024 * 1024 * 2;
  half_t* qp16  = (half_t*)(ws + o); o += (size_t)4096 * 1024 * 2;
  half_t* kswz  = (half_t*)(ws + o); o += (size_t)4096 * 1024 * 2;
  unsigned short* vtl = (unsigned short*)(ws + o); o += (size_t)4096 * 1024 * 2;
  unsigned short* Opart = (unsigned short*)(ws + o); o += (size_t)2 * 65536 * 64 * 2;
  float* rpart = (float*)(ws + o); o += (size_t)2 * 65536 * 4;
  half_t* qs  = q16;    // alias (q16 dead after k_gemm<0>)

  k_cvtbase<<<8196, 256, 0, stream>>>(query, key_, value, wq, wk, wv, wo,
                                      q16, k16, v16, w16, wb1, wb2, nctx, base_v);
  k_gemm<0><<<dim3(8, 32, 3), 256, 0, stream>>>(q16, w16, qp16, kswz, vtl, nullptr);
  k_gate<<<256, 256, 0, stream>>>(qp16, base_v, wg1, wg2, qs);
  k_attn<<<dim3(16, 16, 2), 256, 0, stream>>>(qs, kswz, vtl, Opart, rpart);
  // combine fused into k_gemm<3>: A = (O0+O1)/(r0+r1) computed in staging
  k_gemm<3><<<dim3(8, 32, 1), 256, 0, stream>>>((const half_t*)Opart,
                                                w16 + (size_t)3 * 1048576,
                                                nullptr, nullptr,
                                                (unsigned short*)rpart, out);
}

// Round 13
// 251.133 us; speedup vs baseline: 1.2725x; 1.0587x over previous
//
#include <hip/hip_runtime.h>
#include <math.h>

// ---------------------------------------------------------------------------
// QASS Multihead Attention, MI355X (gfx950)
// B=2, N=2048, D=1024, H=16, Dh=64, HID=64. Output fp32 [B,N,D].
//
// R18 = R15 exact restore (session best, 249.9us). R16 (barrier-free attn)
// spilled to scratch; R17 (combine fused into gemm<3>) hit 8-way ds_write
// bank conflicts + unhidden scatter loads (gemm<3> 13->49us) and perturbed
// attn codegen (+6us, rule #19). Both reverted.
//   - k_gemm: BK=32 double-buffer (2x16KB=32KB, 3 blocks/CU), one barrier
//     per step; LDS-staged z=1/z=2 scatter epilogues.
//   - k_attn: swapped QK^T in-register P path, V global->reg, K dma16
//     double-buffer in LDS, rsum via ones-MFMA, cvt_pk bf16 packing.
// Precision: fp16 projections/QK^T, bf16 P*V and O-partials, fp32 softmax
// (deferred, log2 domain; exp2 never overflows fp32).
// ---------------------------------------------------------------------------

typedef _Float16 half_t;
using half8   = __attribute__((ext_vector_type(8))) _Float16;  // 4 VGPRs
using bhalf8  = __attribute__((ext_vector_type(8))) short;     // 8 bf16
using floatx4 = __attribute__((ext_vector_type(4))) float;     // MFMA C/D

__device__ inline unsigned short f2bf(float f) {
  union { float f; unsigned int u; } v; v.f = f;
  unsigned int u = v.u;
  u = u + 0x7fffu + ((u >> 16) & 1u);
  return (unsigned short)(u >> 16);
}
__device__ inline float bf2f(unsigned short h) {
  union { unsigned int u; float f; } v; v.u = ((unsigned int)h) << 16;
  return v.f;
}
__device__ inline float gelu_f(float x) {      // exact (erf) GELU
  return 0.5f * x * (1.0f + erff(x * 0.70710678118654752440f));
}
__device__ __forceinline__ unsigned int cvtpk_bf16(float lo, float hi) {
  unsigned int r;
  asm("v_cvt_pk_bf16_f32 %0, %1, %2" : "=v"(r) : "v"(lo), "v"(hi));
  return r;
}

#define MFMAF16(a, b, c)  __builtin_amdgcn_mfma_f32_16x16x32_f16((a), (b), (c), 0, 0, 0)
#define MFMABF16(a, b, c) __builtin_amdgcn_mfma_f32_16x16x32_bf16((a), (b), (c), 0, 0, 0)

__device__ __forceinline__ void dma16(const void* g, void* l) {
  __builtin_amdgcn_global_load_lds(
      (const __attribute__((address_space(1))) unsigned int*)g,
      (__attribute__((address_space(3))) unsigned int*)l, 16, 0, 0);
}

// ---------------------------------------------------------------------------
// fp32->fp16 conversion (q/k/v 3x4M + weights 4x1M) and (blocks >= 8192)
// base[1024] = gelu(log(n) * wb1) @ wb2.T
// ---------------------------------------------------------------------------
__global__ __launch_bounds__(256) void k_cvtbase(
    const float* __restrict__ q, const float* __restrict__ k, const float* __restrict__ v,
    const float* __restrict__ wq, const float* __restrict__ wk,
    const float* __restrict__ wv, const float* __restrict__ wo,
    half_t* __restrict__ q16, half_t* __restrict__ k16, half_t* __restrict__ v16,
    half_t* __restrict__ w16,
    const float* __restrict__ wb1, const float* __restrict__ wb2,
    const int* __restrict__ nctx, float* __restrict__ base_out) {
  int tid = threadIdx.x;
  if (blockIdx.x >= 8192) {                    // base path (4 blocks)
    __shared__ float h1[64];
    float logn = logf((float)(*nctx));
    if (tid < 64) h1[tid] = gelu_f(logn * wb1[tid]);
    __syncthreads();
    int i = (blockIdx.x - 8192) * 256 + tid;
    float s = 0.f;
#pragma unroll
    for (int j = 0; j < 64; j++) s += h1[j] * wb2[i * 64 + j];
    base_out[i] = s;
    return;
  }
  size_t e = ((size_t)blockIdx.x * 256 + tid) * 8;
  const float* src; half_t* dst; size_t off;
  if (e < (size_t)3 * 4194304) {
    int t = (int)(e >> 22); off = e & 4194303;
    src = (t == 0) ? q : (t == 1 ? k : v);
    dst = (t == 0) ? q16 : (t == 1 ? k16 : v16);
  } else {
    size_t e2 = e - (size_t)3 * 4194304;
    int t = (int)(e2 >> 20); off = (e2 & 1048575);
    src = (t == 0) ? wq : (t == 1 ? wk : (t == 2 ? wv : wo));
    dst = w16 + (size_t)t * 1048576;
  }
  float4 a = *(const float4*)(src + off);
  float4 b = *(const float4*)(src + off + 4);
  half8 h;
  h[0] = (half_t)a.x; h[1] = (half_t)a.y; h[2] = (half_t)a.z; h[3] = (half_t)a.w;
  h[4] = (half_t)b.x; h[5] = (half_t)b.y; h[6] = (half_t)b.z; h[7] = (half_t)b.w;
  *(half8*)(dst + off) = h;
}

// ---------------------------------------------------------------------------
// fp16 GEMM  C[4096,1024] = A @ W^T, 128x128 tile, BK=32, 4 waves (2x2),
// each wave 64x64 (4x4 frags). BK=32 double-buffered global_load_lds
// staging (2 x 16KB = 32KB): per step {barrier; issue DMA(kk+32 -> buf^1);
// compute buf} -- staging latency hides under compute w/o occupancy loss.
// After the K-loop the 32KB LDS is reused as an epilogue transpose buffer
// for z=1/z=2 (output-linear staging, then 8x coalesced 16B stores/thread).
// MODE 0 (QKV, grid.z selects): z=0 -> qp16 [B,H,N,Dh] fp16 (direct)
//                               z=1 -> kswz fp16 (chunk-swizzled d)
//                               z=2 -> vtl bf16, fragment-linear per tile
//   for the k-permuted PV: key nn (in tile) decomposes kc4=nn>>5,
//   quad=(nn>>2)&3, j=(nn&3)|(((nn>>4)&1)<<2); cell [kc4][lane=quad*16+lm]
//   [dt][j] holds V[key][d=dt*16+lm] (64B/lane contiguous per kc4).
// MODE 3: A=obf fp16 [4096,1024], -> fp32 out (direct)
// ---------------------------------------------------------------------------
template <int MODE>
__global__ __launch_bounds__(256, 3) void k_gemm(const half_t* __restrict__ Abase,
                                                 const half_t* __restrict__ Wbase,
                                                 half_t* __restrict__ qp16,
                                                 half_t* __restrict__ kswz,
                                                 unsigned short* __restrict__ vtl,
                                                 float* __restrict__ outf) {
  const int z = (MODE == 0) ? blockIdx.z : 0;
  const half_t* Ag = Abase + (size_t)z * 4194304;
  const half_t* Wg = Wbase + (size_t)z * 1048576;
  __shared__ __align__(16) half_t SM[4][128 * 32];   // A0,A1,B0,B1; 32 KB
  const int tid = threadIdx.x, lane = tid & 63, w = tid >> 6;
  const int quad = lane >> 4, lm = lane & 15;
  const int wm = w >> 1, wn = w & 1;
  const int bm0 = blockIdx.y * 128, bn0 = blockIdx.x * 128;

  const floatx4 zero4 = {0.f, 0.f, 0.f, 0.f};
  floatx4 acc[4][4];
#pragma unroll
  for (int i = 0; i < 4; i++)
#pragma unroll
    for (int j = 0; j < 4; j++) acc[i][j] = zero4;

  // staging constants (lane-only; bijective per 16-row group)
  const int j4 = lane >> 2;                              // 0..15
  const int cs = (lane & 3) ^ (((j4 & 3) + (j4 >> 2)) & 3);
  const int ub = ((lm & 3) + (lm >> 2)) & 3;             // read-side XOR

  // prologue: stage kk=0 -> buf 0
#pragma unroll
  for (int i = 0; i < 2; i++) {
    int tr = w * 32 + i * 16 + j4;
    dma16((const char*)Ag + ((size_t)(bm0 + tr) * 1024 + cs * 8) * 2,
          (char*)SM[0] + (w * 32 + i * 16) * 64);
    dma16((const char*)Wg + ((size_t)(bn0 + tr) * 1024 + cs * 8) * 2,
          (char*)SM[2] + (w * 32 + i * 16) * 64);
  }

  for (int kk = 0; kk < 1024; kk += 32) {
    const int cur = (kk >> 5) & 1;
    __syncthreads();                 // drains this wave's DMA (buf[cur]) and
                                     // syncs all waves' reads of buf[cur^1]
    if (kk < 992) {
#pragma unroll
      for (int i = 0; i < 2; i++) {
        int tr = w * 32 + i * 16 + j4;
        dma16((const char*)Ag + ((size_t)(bm0 + tr) * 1024 + kk + 32 + cs * 8) * 2,
              (char*)SM[cur ^ 1] + (w * 32 + i * 16) * 64);
        dma16((const char*)Wg + ((size_t)(bn0 + tr) * 1024 + kk + 32 + cs * 8) * 2,
              (char*)SM[2 + (cur ^ 1)] + (w * 32 + i * 16) * 64);
      }
    }

    const half_t* as_ = SM[cur];
    const half_t* bs_ = SM[2 + cur];
    half8 af[4], bf[4];
#pragma unroll
    for (int tm = 0; tm < 4; tm++)
      af[tm] = *(const half8*)&as_[(wm * 64 + tm * 16 + lm) * 32
                                   + ((quad ^ ub) << 3)];
#pragma unroll
    for (int tn = 0; tn < 4; tn++)
      bf[tn] = *(const half8*)&bs_[(wn * 64 + tn * 16 + lm) * 32
                                   + ((quad ^ ub) << 3)];
#pragma unroll
    for (int tm = 0; tm < 4; tm++)
#pragma unroll
      for (int tn = 0; tn < 4; tn++)
        acc[tm][tn] = MFMAF16(af[tm], bf[tn], acc[tm][tn]);
  }

  // ---- epilogue ----
  if constexpr (MODE == 3) {
#pragma unroll
    for (int tm = 0; tm < 4; tm++)
#pragma unroll
      for (int tn = 0; tn < 4; tn++)
#pragma unroll
        for (int rr = 0; rr < 4; rr++) {
          int gm = bm0 + wm * 64 + tm * 16 + quad * 4 + rr;
          int gn = bn0 + wn * 64 + tn * 16 + lm;
          outf[(size_t)gm * 1024 + gn] = acc[tm][tn][rr];
        }
  } else if (z == 0) {
    // direct fp16 stores (per-instruction footprint: 4 x 32B lines -- ok)
#pragma unroll
    for (int tm = 0; tm < 4; tm++)
#pragma unroll
      for (int tn = 0; tn < 4; tn++)
#pragma unroll
        for (int rr = 0; rr < 4; rr++) {
          int gm = bm0 + wm * 64 + tm * 16 + quad * 4 + rr;   // b*2048+n
          int gn = bn0 + wn * 64 + tn * 16 + lm;              // h*64+d
          int b = gm >> 11, n = gm & 2047, hd = gn >> 6, d = gn & 63;
          qp16[((size_t)((b << 4) + hd) * 2048 + n) * 64 + d] = (half_t)acc[tm][tn][rr];
        }
  } else if (z == 1) {
    // LDS-staged: sm[(hl*128+nl)*64 + swz] then linear 16B writes
    half_t* smh = (half_t*)&SM[0][0];
    __syncthreads();                 // K-loop LDS reads complete
#pragma unroll
    for (int tm = 0; tm < 4; tm++)
#pragma unroll
      for (int tn = 0; tn < 4; tn++) {
        int gnl = wn * 64 + tn * 16 + lm;          // local gn 0..127
        int hl = gnl >> 6, d = gnl & 63;
#pragma unroll
        for (int rr = 0; rr < 4; rr++) {
          int nl = wm * 64 + tm * 16 + quad * 4 + rr;
          int sw = ((((d >> 3) ^ (nl & 7)) << 3) | (d & 7));
          smh[(hl * 128 + nl) * 64 + sw] = (half_t)acc[tm][tn][rr];
        }
      }
    __syncthreads();
    {
      const int b = bm0 >> 11, n0 = bm0 & 2047, hd0 = bn0 >> 6;
#pragma unroll
      for (int c = 0; c < 8; c++) {
        int lin = (c * 256 + tid) * 8;
        int hl = lin >> 13, nl = (lin >> 6) & 127, j0 = lin & 63;
        size_t row = (size_t)((b << 4) + hd0 + hl) * 2048 + n0 + nl;
        *(half8*)(kswz + row * 64 + j0) = *(const half8*)(smh + lin);
      }
    }
  } else {
    // z == 2: LDS-staged, rr-packed 8B writes, then linear 16B writes
    unsigned short* sm = (unsigned short*)&SM[0][0];
    __syncthreads();                 // K-loop LDS reads complete
#pragma unroll
    for (int tm = 0; tm < 4; tm++) {
      int nlb = wm * 64 + tm * 16 + quad * 4;      // nl = nlb + rr
      int tl = (nlb >> 6) & 1, nnb = nlb & 63;
      int kc4 = nnb >> 5;
      int qd = (nnb >> 2) & 3;
      int jb = (nnb >> 4) & 1;                     // jj = rr | (jb<<2)
#pragma unroll
      for (int tn = 0; tn < 4; tn++) {
        int gnl = wn * 64 + tn * 16 + lm;
        int hl = gnl >> 6, d = gnl & 63;
        int inner0 = (qd * 16 + (d & 15)) * 32 + (d >> 4) * 8 + jb * 4;
        unsigned int u0 = __float_as_uint(acc[tm][tn][0]) + 0x8000u;
        unsigned int u1 = __float_as_uint(acc[tm][tn][1]) + 0x8000u;
        unsigned int u2 = __float_as_uint(acc[tm][tn][2]) + 0x8000u;
        unsigned int u3 = __float_as_uint(acc[tm][tn][3]) + 0x8000u;
        uint2 pk;
        pk.x = __builtin_amdgcn_perm(u1, u0, 0x07060302u);
        pk.y = __builtin_amdgcn_perm(u3, u2, 0x07060302u);
        *(uint2*)&sm[(((hl * 2 + tl) * 2 + kc4) * 2048) + inner0] = pk;
      }
    }
    __syncthreads();
    {
      const int b = bm0 >> 11, t0 = (bm0 & 2047) >> 6, hd0 = bn0 >> 6;
#pragma unroll
      for (int c = 0; c < 8; c++) {
        int lin = (c * 256 + tid) * 8;
        int page = lin >> 11;
        int hl = page >> 2, tl = (page >> 1) & 1, kc4 = page & 1;
        int inner = lin & 2047;
        size_t idx = ((size_t)(((b << 4) + hd0 + hl) * 32 + t0 + tl) * 2 + kc4) * 2048
                   + (size_t)inner;
        *(bhalf8*)(vtl + idx) = *(const bhalf8*)(sm + lin);
      }
    }
  }
}

// ---------------------------------------------------------------------------
// Gate MLP via fp16 MFMA. 256 rows/block (4 waves x 4 tiles of 16 rows).
// h = gelu(q @ wg1^T)  [LDS C->A round-trip]  t = h @ wg2^T,
// qs = q * base * (1+tanh(t)) * (1/8)*log2(e), fp16.
// ---------------------------------------------------------------------------
__global__ __launch_bounds__(256) void k_gate(const half_t* __restrict__ qp,
                                              const float* __restrict__ base_v,
                                              const float* __restrict__ wg1,
                                              const float* __restrict__ wg2,
                                              half_t* __restrict__ qs) {
  __shared__ __align__(16) half_t W1[64 * 72];
  __shared__ __align__(16) half_t W2[64 * 72];
  __shared__ __align__(16) half_t HT[4][16 * 72];
  const int tid = threadIdx.x, lane = tid & 63, w = tid >> 6;
  const int quad = lane >> 4, lm = lane & 15;
  for (int i = tid; i < 4096; i += 256) {
    int j = i >> 6, d = i & 63;
    W1[j * 72 + d] = (half_t)wg1[i];
    W2[j * 72 + d] = (half_t)wg2[i];
  }
  __syncthreads();
  const int R0 = blockIdx.x * 256;
  const int hd = (R0 >> 11) & 15;
  float bsev[4];
#pragma unroll
  for (int tn = 0; tn < 4; tn++) bsev[tn] = base_v[hd * 64 + tn * 16 + lm];
  const float cs = 0.18033688011112042f;       // (1/8)*log2(e)
  const floatx4 zero4 = {0.f, 0.f, 0.f, 0.f};
  half_t* ht = HT[w];

  for (int ti = 0; ti < 4; ti++) {
    int r0 = R0 + w * 64 + ti * 16;
    half8 aq0 = *(const half8*)&qp[(size_t)(r0 + lm) * 64 + quad * 8];
    half8 aq1 = *(const half8*)&qp[(size_t)(r0 + lm) * 64 + 32 + quad * 8];
    floatx4 hc[4];
#pragma unroll
    for (int tn = 0; tn < 4; tn++) {
      half8 b0 = *(const half8*)&W1[(tn * 16 + lm) * 72 + quad * 8];
      half8 b1 = *(const half8*)&W1[(tn * 16 + lm) * 72 + 32 + quad * 8];
      floatx4 t = zero4;
      t = MFMAF16(aq0, b0, t);
      t = MFMAF16(aq1, b1, t);
      hc[tn] = t;
    }
#pragma unroll
    for (int tn = 0; tn < 4; tn++)
#pragma unroll
      for (int rr = 0; rr < 4; rr++)
        ht[(quad * 4 + rr) * 72 + tn * 16 + lm] = (half_t)gelu_f(hc[tn][rr]);
    // layer 2 (A-frags from per-wave LDS; in-order LDS per wave)
    half8 ah0 = *(const half8*)&ht[lm * 72 + quad * 8];
    half8 ah1 = *(const half8*)&ht[lm * 72 + 32 + quad * 8];
#pragma unroll
    for (int tn = 0; tn < 4; tn++) {
      half8 b0 = *(const half8*)&W2[(tn * 16 + lm) * 72 + quad * 8];
      half8 b1 = *(const half8*)&W2[(tn * 16 + lm) * 72 + 32 + quad * 8];
      floatx4 t = zero4;
      t = MFMAF16(ah0, b0, t);
      t = MFMAF16(ah1, b1, t);
#pragma unroll
      for (int rr = 0; rr < 4; rr++) {
        int row = r0 + quad * 4 + rr;
        int d = tn * 16 + lm;
        float qv = (float)qp[(size_t)row * 64 + d];
        float g = 1.0f + tanhf(t[rr]);
        qs[(size_t)row * 64 + d] = (half_t)(qv * bsev[tn] * g * cs);
      }
    }
  }
}

// ---------------------------------------------------------------------------
// Flash attention, deferred softmax, swapped QK^T, in-register P path.
// Grid (16 hd, 8 qg x 2 half, 2 b) = 512 blocks x 256 thr -> 2 blocks/CU;
// same-head blocks pinned to one XCD. Each block: 256 q-rows x 1024 keys
// (16 tiles of 64). Per wave: 64 q-rows (4 rg, 2 pairs).
// K staged via dma16 double-buffer in LDS (only LDS user, 16 KB);
// V global->reg (fragment-linear vtl, L2-resident).
// s = mfma(K,Q): lane holds P[q=lm][k=quad*4+rr+16kb]; PV k-axis permuted
// (phys k = 32kc4+quad*4+(j&3)+16(j>>2)) so cvt_pk-packed exp2 results feed
// MFMABF16 A-fragment directly -- no LDS round-trip. rsum via ones-MFMA
// (row-sum of the same bf16 P; no VALU adds, no epilogue shuffles).
// ---------------------------------------------------------------------------
__global__ __launch_bounds__(256, 2) void k_attn(const half_t* __restrict__ qs,
                                                 const half_t* __restrict__ kswz,
                                                 const unsigned short* __restrict__ vtl,
                                                 unsigned short* __restrict__ Opart,
                                                 float* __restrict__ rpart) {
  __shared__ __align__(16) half_t KH[2][64 * 64];           // 2 x 8 KB

  const int tid = threadIdx.x;
  const int lane = tid & 63;
  const int w = tid >> 6;            // 0..3
  const int quad = lane >> 4;
  const int lm = lane & 15;
  const int a7 = lm & 7;
  const int hd = blockIdx.x;
  const int qg = blockIdx.y >> 1, half = blockIdx.y & 1;
  const int b = blockIdx.z;
  const int bh = b * 16 + hd;
  const size_t hb = (size_t)bh * 2048 * 64;
  const char* khT = (const char*)(kswz + hb);
  const unsigned short* vtT = vtl + (size_t)bh * 32 * 4096;

  half8 qh[4][2];
#pragma unroll
  for (int rg = 0; rg < 4; rg++)
#pragma unroll
    for (int kc = 0; kc < 2; kc++)
      qh[rg][kc] = *(const half8*)(qs + hb
          + (size_t)(qg * 256 + w * 64 + rg * 16 + lm) * 64 + kc * 32 + quad * 8);

  const floatx4 zero4 = {0.f, 0.f, 0.f, 0.f};
  floatx4 O[4][4];
#pragma unroll
  for (int rg = 0; rg < 4; rg++)
#pragma unroll
    for (int dt = 0; dt < 4; dt++) O[rg][dt] = zero4;
  floatx4 racc[4];                   // rsum accumulators (ones-MFMA)
#pragma unroll
  for (int rg = 0; rg < 4; rg++) racc[rg] = zero4;
  const short one_bf = (short)0x3F80;           // bf16 1.0
  const bhalf8 vones = {one_bf, one_bf, one_bf, one_bf,
                        one_bf, one_bf, one_bf, one_bf};

  const int lo16 = lane * 16;
  const size_t g0 = (size_t)half * 16 * 8192;

  // prologue: stage K tile 0 of this half (2 dma16/wave)
#pragma unroll
  for (int r = 0; r < 2; r++) {
    int sb = (w * 2 + r) * 1024;
    dma16(khT + g0 + sb + lo16, (char*)KH[0] + sb);
  }

  for (int t = 0; t < 16; t++) {
    const int cur = t & 1;
    __syncthreads();

    // V fragments global->reg (issued first; PV's vmcnt wait then leaves
    // the younger K-dma prefetch in flight)
    const unsigned short* vb = vtT + ((size_t)(half * 16 + t) * 2) * 2048 + lane * 32;
    bhalf8 vf[2][4];
#pragma unroll
    for (int kc4 = 0; kc4 < 2; kc4++)
#pragma unroll
      for (int dt = 0; dt < 4; dt++)
        vf[kc4][dt] = *(const bhalf8*)(vb + kc4 * 2048 + dt * 8);

    if (t < 15) {
      const size_t gof = g0 + (size_t)(t + 1) * 8192;
#pragma unroll
      for (int r = 0; r < 2; r++) {
        int sb = (w * 2 + r) * 1024;
        dma16(khT + gof + sb + lo16, (char*)KH[cur ^ 1] + sb);
      }
    }

    const half_t* kh_ = KH[cur];

#pragma unroll
    for (int p = 0; p < 2; p++) {
      floatx4 s[2][4];
#pragma unroll
      for (int ri = 0; ri < 2; ri++)
#pragma unroll
        for (int kb = 0; kb < 4; kb++) s[ri][kb] = zero4;

      __builtin_amdgcn_s_setprio(1);
#pragma unroll
      for (int kb = 0; kb < 4; kb++)
#pragma unroll
        for (int kc = 0; kc < 2; kc++) {
          int addr = (kb * 16 + lm) * 64 + (((kc * 4 + quad) ^ a7) << 3);
          half8 khf = *(const half8*)&kh_[addr];
          // swapped: A = K (rows=keys), B = Q (cols=q-rows)
#pragma unroll
          for (int ri = 0; ri < 2; ri++)
            s[ri][kb] = MFMAF16(khf, qh[p * 2 + ri][kc], s[ri][kb]);
        }
      __builtin_amdgcn_s_setprio(0);

#pragma unroll
      for (int ri = 0; ri < 2; ri++) {
        const int rg = p * 2 + ri;
        // exp2 of all 16 in-lane scores (q-row lm, keys quad*4+rr+16kb)
        float e[4][4];
#pragma unroll
        for (int kb = 0; kb < 4; kb++)
#pragma unroll
          for (int rr = 0; rr < 4; rr++)
            e[kb][rr] = __builtin_amdgcn_exp2f(s[ri][kb][rr]);

        __builtin_amdgcn_s_setprio(1);
#pragma unroll
        for (int kc4 = 0; kc4 < 2; kc4++) {
          union { unsigned int w4[4]; bhalf8 v; } pa;
          pa.w4[0] = cvtpk_bf16(e[2 * kc4][0],     e[2 * kc4][1]);
          pa.w4[1] = cvtpk_bf16(e[2 * kc4][2],     e[2 * kc4][3]);
          pa.w4[2] = cvtpk_bf16(e[2 * kc4 + 1][0], e[2 * kc4 + 1][1]);
          pa.w4[3] = cvtpk_bf16(e[2 * kc4 + 1][2], e[2 * kc4 + 1][3]);
          racc[rg] = MFMABF16(pa.v, vones, racc[rg]);   // row-sum of P
#pragma unroll
          for (int dt = 0; dt < 4; dt++)
            O[rg][dt] = MFMABF16(pa.v, vf[kc4][dt], O[rg][dt]);
        }
        __builtin_amdgcn_s_setprio(0);
      }
    }
  }

  // epilogue: rsum direct from racc (row = quad*4+rr, same as O) and
  // bf16 O-partials
  unsigned short* op = Opart + (size_t)half * 65536 * 64;
  float* rp = rpart + (size_t)half * 65536;
#pragma unroll
  for (int rg = 0; rg < 4; rg++) {
#pragma unroll
    for (int rr = 0; rr < 4; rr++) {
      int n = qg * 256 + w * 64 + rg * 16 + quad * 4 + rr;
      size_t row = (size_t)bh * 2048 + n;
      if (lm == 0) rp[row] = racc[rg][rr];
#pragma unroll
      for (int dt = 0; dt < 4; dt++)
        op[row * 64 + dt * 16 + lm] = f2bf(O[rg][dt][rr]);
    }
  }
}

// ---------------------------------------------------------------------------
// combine: o = (O0+O1)/(r0+r1) -> obf fp16 [4096,1024] (out-proj A layout)
// ---------------------------------------------------------------------------
__global__ __launch_bounds__(256) void k_combine(const unsigned short* __restrict__ Opart,
                                                 const float* __restrict__ rpart,
                                                 half_t* __restrict__ obf) {
  size_t e = ((size_t)blockIdx.x * 256 + threadIdx.x) * 8;
  size_t row = e >> 6; int d0 = (int)(e & 63);
  float inv = 1.0f / (rpart[row] + rpart[65536 + row]);
  bhalf8 o0 = *(const bhalf8*)&Opart[row * 64 + d0];
  bhalf8 o1 = *(const bhalf8*)&Opart[(size_t)65536 * 64 + row * 64 + d0];
  int b = (int)(row >> 15), h = (int)((row >> 11) & 15), n = (int)(row & 2047);
  half8 o;
#pragma unroll
  for (int j = 0; j < 8; j++)
    o[j] = (half_t)((bf2f((unsigned short)o0[j]) + bf2f((unsigned short)o1[j])) * inv);
  *(half8*)&obf[((size_t)(b * 2048 + n)) * 1024 + h * 64 + d0] = o;
}

// ---------------------------------------------------------------------------
extern "C" void kernel_launch(void* const* d_in, const int* in_sizes, int n_in,
                              void* d_out, int out_size, void* d_ws, size_t ws_size,
                              hipStream_t stream) {
  const float* query = (const float*)d_in[0];
  const float* key_  = (const float*)d_in[1];
  const float* value = (const float*)d_in[2];
  const float* wq  = (const float*)d_in[4];
  const float* wk  = (const float*)d_in[5];
  const float* wv  = (const float*)d_in[6];
  const float* wo  = (const float*)d_in[7];
  const float* wb1 = (const float*)d_in[8];
  const float* wb2 = (const float*)d_in[9];
  const float* wg1 = (const float*)d_in[10];
  const float* wg2 = (const float*)d_in[11];
  const int* nctx  = (const int*)d_in[12];
  float* out = (float*)d_out;

  char* ws = (char*)d_ws;
  size_t o = 0;
  float* base_v = (float*)(ws + o); o += 4096;
  half_t* q16   = (half_t*)(ws + o); o += (size_t)4096 * 1024 * 2;   // later: qs
  half_t* k16   = (half_t*)(ws + o); o += (size_t)4096 * 1024 * 2;   // later: obf
  half_t* v16   = (half_t*)(ws + o); o += (size_t)4096 * 1024 * 2;
  half_t* w16   = (half_t*)(ws + o); o += (size_t)4 * 1024 * 1024 * 2;
  half_t* qp16  = (half_t*)(ws + o); o += (size_t)4096 * 1024 * 2;
  half_t* kswz  = (half_t*)(ws + o); o += (size_t)4096 * 1024 * 2;
  unsigned short* vtl = (unsigned short*)(ws + o); o += (size_t)4096 * 1024 * 2;
  unsigned short* Opart = (unsigned short*)(ws + o); o += (size_t)2 * 65536 * 64 * 2;
  float* rpart = (float*)(ws + o); o += (size_t)2 * 65536 * 4;
  half_t* qs  = q16;    // aliases (q16/k16 dead after k_gemm<0>)
  half_t* obf = k16;

  k_cvtbase<<<8196, 256, 0, stream>>>(query, key_, value, wq, wk, wv, wo,
                                      q16, k16, v16, w16, wb1, wb2, nctx, base_v);
  k_gemm<0><<<dim3(8, 32, 3), 256, 0, stream>>>(q16, w16, qp16, kswz, vtl, nullptr);
  k_gate<<<256, 256, 0, stream>>>(qp16, base_v, wg1, wg2, qs);
  k_attn<<<dim3(16, 16, 2), 256, 0, stream>>>(qs, kswz, vtl, Opart, rpart);
  k_combine<<<2048, 256, 0, stream>>>(Opart, rpart, obf);
  k_gemm<3><<<dim3(8, 32, 1), 256, 0, stream>>>(obf, w16 + (size_t)3 * 1048576,
                                                nullptr, nullptr, nullptr, out);
}

// Round 14
// 241.862 us; speedup vs baseline: 1.3213x; 1.0383x over previous
//
#include <hip/hip_runtime.h>
#include <math.h>

// ---------------------------------------------------------------------------
// QASS Multihead Attention, MI355X (gfx950)
// B=2, N=2048, D=1024, H=16, Dh=64, HID=64. Output fp32 [B,N,D].
//
// R19 = R18/R15 + two micro-fixes:
//   (1) k_attn: K-fragment LDS reads hoisted out of the p-loop into kf[8]
//       (VGPR 100->~130, cap 256 @ 2 waves/SIMD) -- halves per-tile K
//       ds_read_b128 count (compiler provably wasn't CSE-ing: VGPR=100).
//   (2) k_gate: 512 blocks x 128 rows (was 256 x 256) -> 2 blocks/CU to
//       interleave the serial MFMA->gelu->LDS->MFMA->tanh chain.
// Everything else byte-identical to R18 (session best, ~250us):
//   - k_gemm: BK=32 double-buffer (2x16KB=32KB, 3 blocks/CU), one barrier
//     per step; LDS-staged z=1/z=2 scatter epilogues.
//   - k_attn: swapped QK^T in-register P path, V global->reg, K dma16
//     double-buffer in LDS, rsum via ones-MFMA, cvt_pk bf16 packing.
// Precision: fp16 projections/QK^T, bf16 P*V and O-partials, fp32 softmax
// (deferred, log2 domain; exp2 never overflows fp32).
// ---------------------------------------------------------------------------

typedef _Float16 half_t;
using half8   = __attribute__((ext_vector_type(8))) _Float16;  // 4 VGPRs
using bhalf8  = __attribute__((ext_vector_type(8))) short;     // 8 bf16
using floatx4 = __attribute__((ext_vector_type(4))) float;     // MFMA C/D

__device__ inline unsigned short f2bf(float f) {
  union { float f; unsigned int u; } v; v.f = f;
  unsigned int u = v.u;
  u = u + 0x7fffu + ((u >> 16) & 1u);
  return (unsigned short)(u >> 16);
}
__device__ inline float bf2f(unsigned short h) {
  union { unsigned int u; float f; } v; v.u = ((unsigned int)h) << 16;
  return v.f;
}
__device__ inline float gelu_f(float x) {      // exact (erf) GELU
  return 0.5f * x * (1.0f + erff(x * 0.70710678118654752440f));
}
__device__ __forceinline__ unsigned int cvtpk_bf16(float lo, float hi) {
  unsigned int r;
  asm("v_cvt_pk_bf16_f32 %0, %1, %2" : "=v"(r) : "v"(lo), "v"(hi));
  return r;
}

#define MFMAF16(a, b, c)  __builtin_amdgcn_mfma_f32_16x16x32_f16((a), (b), (c), 0, 0, 0)
#define MFMABF16(a, b, c) __builtin_amdgcn_mfma_f32_16x16x32_bf16((a), (b), (c), 0, 0, 0)

__device__ __forceinline__ void dma16(const void* g, void* l) {
  __builtin_amdgcn_global_load_lds(
      (const __attribute__((address_space(1))) unsigned int*)g,
      (__attribute__((address_space(3))) unsigned int*)l, 16, 0, 0);
}

// ---------------------------------------------------------------------------
// fp32->fp16 conversion (q/k/v 3x4M + weights 4x1M) and (blocks >= 8192)
// base[1024] = gelu(log(n) * wb1) @ wb2.T
// ---------------------------------------------------------------------------
__global__ __launch_bounds__(256) void k_cvtbase(
    const float* __restrict__ q, const float* __restrict__ k, const float* __restrict__ v,
    const float* __restrict__ wq, const float* __restrict__ wk,
    const float* __restrict__ wv, const float* __restrict__ wo,
    half_t* __restrict__ q16, half_t* __restrict__ k16, half_t* __restrict__ v16,
    half_t* __restrict__ w16,
    const float* __restrict__ wb1, const float* __restrict__ wb2,
    const int* __restrict__ nctx, float* __restrict__ base_out) {
  int tid = threadIdx.x;
  if (blockIdx.x >= 8192) {                    // base path (4 blocks)
    __shared__ float h1[64];
    float logn = logf((float)(*nctx));
    if (tid < 64) h1[tid] = gelu_f(logn * wb1[tid]);
    __syncthreads();
    int i = (blockIdx.x - 8192) * 256 + tid;
    float s = 0.f;
#pragma unroll
    for (int j = 0; j < 64; j++) s += h1[j] * wb2[i * 64 + j];
    base_out[i] = s;
    return;
  }
  size_t e = ((size_t)blockIdx.x * 256 + tid) * 8;
  const float* src; half_t* dst; size_t off;
  if (e < (size_t)3 * 4194304) {
    int t = (int)(e >> 22); off = e & 4194303;
    src = (t == 0) ? q : (t == 1 ? k : v);
    dst = (t == 0) ? q16 : (t == 1 ? k16 : v16);
  } else {
    size_t e2 = e - (size_t)3 * 4194304;
    int t = (int)(e2 >> 20); off = (e2 & 1048575);
    src = (t == 0) ? wq : (t == 1 ? wk : (t == 2 ? wv : wo));
    dst = w16 + (size_t)t * 1048576;
  }
  float4 a = *(const float4*)(src + off);
  float4 b = *(const float4*)(src + off + 4);
  half8 h;
  h[0] = (half_t)a.x; h[1] = (half_t)a.y; h[2] = (half_t)a.z; h[3] = (half_t)a.w;
  h[4] = (half_t)b.x; h[5] = (half_t)b.y; h[6] = (half_t)b.z; h[7] = (half_t)b.w;
  *(half8*)(dst + off) = h;
}

// ---------------------------------------------------------------------------
// fp16 GEMM  C[4096,1024] = A @ W^T, 128x128 tile, BK=32, 4 waves (2x2),
// each wave 64x64 (4x4 frags). BK=32 double-buffered global_load_lds
// staging (2 x 16KB = 32KB): per step {barrier; issue DMA(kk+32 -> buf^1);
// compute buf} -- staging latency hides under compute w/o occupancy loss.
// After the K-loop the 32KB LDS is reused as an epilogue transpose buffer
// for z=1/z=2 (output-linear staging, then 8x coalesced 16B stores/thread).
// MODE 0 (QKV, grid.z selects): z=0 -> qp16 [B,H,N,Dh] fp16 (direct)
//                               z=1 -> kswz fp16 (chunk-swizzled d)
//                               z=2 -> vtl bf16, fragment-linear per tile
//   for the k-permuted PV: key nn (in tile) decomposes kc4=nn>>5,
//   quad=(nn>>2)&3, j=(nn&3)|(((nn>>4)&1)<<2); cell [kc4][lane=quad*16+lm]
//   [dt][j] holds V[key][d=dt*16+lm] (64B/lane contiguous per kc4).
// MODE 3: A=obf fp16 [4096,1024], -> fp32 out (direct)
// ---------------------------------------------------------------------------
template <int MODE>
__global__ __launch_bounds__(256, 3) void k_gemm(const half_t* __restrict__ Abase,
                                                 const half_t* __restrict__ Wbase,
                                                 half_t* __restrict__ qp16,
                                                 half_t* __restrict__ kswz,
                                                 unsigned short* __restrict__ vtl,
                                                 float* __restrict__ outf) {
  const int z = (MODE == 0) ? blockIdx.z : 0;
  const half_t* Ag = Abase + (size_t)z * 4194304;
  const half_t* Wg = Wbase + (size_t)z * 1048576;
  __shared__ __align__(16) half_t SM[4][128 * 32];   // A0,A1,B0,B1; 32 KB
  const int tid = threadIdx.x, lane = tid & 63, w = tid >> 6;
  const int quad = lane >> 4, lm = lane & 15;
  const int wm = w >> 1, wn = w & 1;
  const int bm0 = blockIdx.y * 128, bn0 = blockIdx.x * 128;

  const floatx4 zero4 = {0.f, 0.f, 0.f, 0.f};
  floatx4 acc[4][4];
#pragma unroll
  for (int i = 0; i < 4; i++)
#pragma unroll
    for (int j = 0; j < 4; j++) acc[i][j] = zero4;

  // staging constants (lane-only; bijective per 16-row group)
  const int j4 = lane >> 2;                              // 0..15
  const int cs = (lane & 3) ^ (((j4 & 3) + (j4 >> 2)) & 3);
  const int ub = ((lm & 3) + (lm >> 2)) & 3;             // read-side XOR

  // prologue: stage kk=0 -> buf 0
#pragma unroll
  for (int i = 0; i < 2; i++) {
    int tr = w * 32 + i * 16 + j4;
    dma16((const char*)Ag + ((size_t)(bm0 + tr) * 1024 + cs * 8) * 2,
          (char*)SM[0] + (w * 32 + i * 16) * 64);
    dma16((const char*)Wg + ((size_t)(bn0 + tr) * 1024 + cs * 8) * 2,
          (char*)SM[2] + (w * 32 + i * 16) * 64);
  }

  for (int kk = 0; kk < 1024; kk += 32) {
    const int cur = (kk >> 5) & 1;
    __syncthreads();                 // drains this wave's DMA (buf[cur]) and
                                     // syncs all waves' reads of buf[cur^1]
    if (kk < 992) {
#pragma unroll
      for (int i = 0; i < 2; i++) {
        int tr = w * 32 + i * 16 + j4;
        dma16((const char*)Ag + ((size_t)(bm0 + tr) * 1024 + kk + 32 + cs * 8) * 2,
              (char*)SM[cur ^ 1] + (w * 32 + i * 16) * 64);
        dma16((const char*)Wg + ((size_t)(bn0 + tr) * 1024 + kk + 32 + cs * 8) * 2,
              (char*)SM[2 + (cur ^ 1)] + (w * 32 + i * 16) * 64);
      }
    }

    const half_t* as_ = SM[cur];
    const half_t* bs_ = SM[2 + cur];
    half8 af[4], bf[4];
#pragma unroll
    for (int tm = 0; tm < 4; tm++)
      af[tm] = *(const half8*)&as_[(wm * 64 + tm * 16 + lm) * 32
                                   + ((quad ^ ub) << 3)];
#pragma unroll
    for (int tn = 0; tn < 4; tn++)
      bf[tn] = *(const half8*)&bs_[(wn * 64 + tn * 16 + lm) * 32
                                   + ((quad ^ ub) << 3)];
#pragma unroll
    for (int tm = 0; tm < 4; tm++)
#pragma unroll
      for (int tn = 0; tn < 4; tn++)
        acc[tm][tn] = MFMAF16(af[tm], bf[tn], acc[tm][tn]);
  }

  // ---- epilogue ----
  if constexpr (MODE == 3) {
#pragma unroll
    for (int tm = 0; tm < 4; tm++)
#pragma unroll
      for (int tn = 0; tn < 4; tn++)
#pragma unroll
        for (int rr = 0; rr < 4; rr++) {
          int gm = bm0 + wm * 64 + tm * 16 + quad * 4 + rr;
          int gn = bn0 + wn * 64 + tn * 16 + lm;
          outf[(size_t)gm * 1024 + gn] = acc[tm][tn][rr];
        }
  } else if (z == 0) {
    // direct fp16 stores (per-instruction footprint: 4 x 32B lines -- ok)
#pragma unroll
    for (int tm = 0; tm < 4; tm++)
#pragma unroll
      for (int tn = 0; tn < 4; tn++)
#pragma unroll
        for (int rr = 0; rr < 4; rr++) {
          int gm = bm0 + wm * 64 + tm * 16 + quad * 4 + rr;   // b*2048+n
          int gn = bn0 + wn * 64 + tn * 16 + lm;              // h*64+d
          int b = gm >> 11, n = gm & 2047, hd = gn >> 6, d = gn & 63;
          qp16[((size_t)((b << 4) + hd) * 2048 + n) * 64 + d] = (half_t)acc[tm][tn][rr];
        }
  } else if (z == 1) {
    // LDS-staged: sm[(hl*128+nl)*64 + swz] then linear 16B writes
    half_t* smh = (half_t*)&SM[0][0];
    __syncthreads();                 // K-loop LDS reads complete
#pragma unroll
    for (int tm = 0; tm < 4; tm++)
#pragma unroll
      for (int tn = 0; tn < 4; tn++) {
        int gnl = wn * 64 + tn * 16 + lm;          // local gn 0..127
        int hl = gnl >> 6, d = gnl & 63;
#pragma unroll
        for (int rr = 0; rr < 4; rr++) {
          int nl = wm * 64 + tm * 16 + quad * 4 + rr;
          int sw = ((((d >> 3) ^ (nl & 7)) << 3) | (d & 7));
          smh[(hl * 128 + nl) * 64 + sw] = (half_t)acc[tm][tn][rr];
        }
      }
    __syncthreads();
    {
      const int b = bm0 >> 11, n0 = bm0 & 2047, hd0 = bn0 >> 6;
#pragma unroll
      for (int c = 0; c < 8; c++) {
        int lin = (c * 256 + tid) * 8;
        int hl = lin >> 13, nl = (lin >> 6) & 127, j0 = lin & 63;
        size_t row = (size_t)((b << 4) + hd0 + hl) * 2048 + n0 + nl;
        *(half8*)(kswz + row * 64 + j0) = *(const half8*)(smh + lin);
      }
    }
  } else {
    // z == 2: LDS-staged, rr-packed 8B writes, then linear 16B writes
    unsigned short* sm = (unsigned short*)&SM[0][0];
    __syncthreads();                 // K-loop LDS reads complete
#pragma unroll
    for (int tm = 0; tm < 4; tm++) {
      int nlb = wm * 64 + tm * 16 + quad * 4;      // nl = nlb + rr
      int tl = (nlb >> 6) & 1, nnb = nlb & 63;
      int kc4 = nnb >> 5;
      int qd = (nnb >> 2) & 3;
      int jb = (nnb >> 4) & 1;                     // jj = rr | (jb<<2)
#pragma unroll
      for (int tn = 0; tn < 4; tn++) {
        int gnl = wn * 64 + tn * 16 + lm;
        int hl = gnl >> 6, d = gnl & 63;
        int inner0 = (qd * 16 + (d & 15)) * 32 + (d >> 4) * 8 + jb * 4;
        unsigned int u0 = __float_as_uint(acc[tm][tn][0]) + 0x8000u;
        unsigned int u1 = __float_as_uint(acc[tm][tn][1]) + 0x8000u;
        unsigned int u2 = __float_as_uint(acc[tm][tn][2]) + 0x8000u;
        unsigned int u3 = __float_as_uint(acc[tm][tn][3]) + 0x8000u;
        uint2 pk;
        pk.x = __builtin_amdgcn_perm(u1, u0, 0x07060302u);
        pk.y = __builtin_amdgcn_perm(u3, u2, 0x07060302u);
        *(uint2*)&sm[(((hl * 2 + tl) * 2 + kc4) * 2048) + inner0] = pk;
      }
    }
    __syncthreads();
    {
      const int b = bm0 >> 11, t0 = (bm0 & 2047) >> 6, hd0 = bn0 >> 6;
#pragma unroll
      for (int c = 0; c < 8; c++) {
        int lin = (c * 256 + tid) * 8;
        int page = lin >> 11;
        int hl = page >> 2, tl = (page >> 1) & 1, kc4 = page & 1;
        int inner = lin & 2047;
        size_t idx = ((size_t)(((b << 4) + hd0 + hl) * 32 + t0 + tl) * 2 + kc4) * 2048
                   + (size_t)inner;
        *(bhalf8*)(vtl + idx) = *(const bhalf8*)(sm + lin);
      }
    }
  }
}

// ---------------------------------------------------------------------------
// Gate MLP via fp16 MFMA. 128 rows/block (4 waves x 2 tiles of 16 rows),
// 512 blocks -> 2 blocks/CU (was 256 x 256 rows = 1 block/CU).
// h = gelu(q @ wg1^T)  [LDS C->A round-trip]  t = h @ wg2^T,
// qs = q * base * (1+tanh(t)) * (1/8)*log2(e), fp16.
// ---------------------------------------------------------------------------
__global__ __launch_bounds__(256) void k_gate(const half_t* __restrict__ qp,
                                              const float* __restrict__ base_v,
                                              const float* __restrict__ wg1,
                                              const float* __restrict__ wg2,
                                              half_t* __restrict__ qs) {
  __shared__ __align__(16) half_t W1[64 * 72];
  __shared__ __align__(16) half_t W2[64 * 72];
  __shared__ __align__(16) half_t HT[4][16 * 72];
  const int tid = threadIdx.x, lane = tid & 63, w = tid >> 6;
  const int quad = lane >> 4, lm = lane & 15;
  for (int i = tid; i < 4096; i += 256) {
    int j = i >> 6, d = i & 63;
    W1[j * 72 + d] = (half_t)wg1[i];
    W2[j * 72 + d] = (half_t)wg2[i];
  }
  __syncthreads();
  const int R0 = blockIdx.x * 128;
  const int hd = (R0 >> 11) & 15;
  float bsev[4];
#pragma unroll
  for (int tn = 0; tn < 4; tn++) bsev[tn] = base_v[hd * 64 + tn * 16 + lm];
  const float cs = 0.18033688011112042f;       // (1/8)*log2(e)
  const floatx4 zero4 = {0.f, 0.f, 0.f, 0.f};
  half_t* ht = HT[w];

  for (int ti = 0; ti < 2; ti++) {
    int r0 = R0 + w * 32 + ti * 16;
    half8 aq0 = *(const half8*)&qp[(size_t)(r0 + lm) * 64 + quad * 8];
    half8 aq1 = *(const half8*)&qp[(size_t)(r0 + lm) * 64 + 32 + quad * 8];
    floatx4 hc[4];
#pragma unroll
    for (int tn = 0; tn < 4; tn++) {
      half8 b0 = *(const half8*)&W1[(tn * 16 + lm) * 72 + quad * 8];
      half8 b1 = *(const half8*)&W1[(tn * 16 + lm) * 72 + 32 + quad * 8];
      floatx4 t = zero4;
      t = MFMAF16(aq0, b0, t);
      t = MFMAF16(aq1, b1, t);
      hc[tn] = t;
    }
#pragma unroll
    for (int tn = 0; tn < 4; tn++)
#pragma unroll
      for (int rr = 0; rr < 4; rr++)
        ht[(quad * 4 + rr) * 72 + tn * 16 + lm] = (half_t)gelu_f(hc[tn][rr]);
    // layer 2 (A-frags from per-wave LDS; in-order LDS per wave)
    half8 ah0 = *(const half8*)&ht[lm * 72 + quad * 8];
    half8 ah1 = *(const half8*)&ht[lm * 72 + 32 + quad * 8];
#pragma unroll
    for (int tn = 0; tn < 4; tn++) {
      half8 b0 = *(const half8*)&W2[(tn * 16 + lm) * 72 + quad * 8];
      half8 b1 = *(const half8*)&W2[(tn * 16 + lm) * 72 + 32 + quad * 8];
      floatx4 t = zero4;
      t = MFMAF16(ah0, b0, t);
      t = MFMAF16(ah1, b1, t);
#pragma unroll
      for (int rr = 0; rr < 4; rr++) {
        int row = r0 + quad * 4 + rr;
        int d = tn * 16 + lm;
        float qv = (float)qp[(size_t)row * 64 + d];
        float g = 1.0f + tanhf(t[rr]);
        qs[(size_t)row * 64 + d] = (half_t)(qv * bsev[tn] * g * cs);
      }
    }
  }
}

// ---------------------------------------------------------------------------
// Flash attention, deferred softmax, swapped QK^T, in-register P path.
// Grid (16 hd, 8 qg x 2 half, 2 b) = 512 blocks x 256 thr -> 2 blocks/CU;
// same-head blocks pinned to one XCD. Each block: 256 q-rows x 1024 keys
// (16 tiles of 64). Per wave: 64 q-rows (4 rg, 2 pairs).
// K staged via dma16 double-buffer in LDS (only LDS user, 16 KB);
// V global->reg (fragment-linear vtl, L2-resident).
// s = mfma(K,Q): lane holds P[q=lm][k=quad*4+rr+16kb]; PV k-axis permuted
// (phys k = 32kc4+quad*4+(j&3)+16(j>>2)) so cvt_pk-packed exp2 results feed
// MFMABF16 A-fragment directly -- no LDS round-trip. rsum via ones-MFMA.
// R19: K fragments read ONCE per tile into kf[8] (p-invariant addresses;
// compiler wasn't CSE-ing them -- VGPR was 100, needs ~130 to hold).
// ---------------------------------------------------------------------------
__global__ __launch_bounds__(256, 2) void k_attn(const half_t* __restrict__ qs,
                                                 const half_t* __restrict__ kswz,
                                                 const unsigned short* __restrict__ vtl,
                                                 unsigned short* __restrict__ Opart,
                                                 float* __restrict__ rpart) {
  __shared__ __align__(16) half_t KH[2][64 * 64];           // 2 x 8 KB

  const int tid = threadIdx.x;
  const int lane = tid & 63;
  const int w = tid >> 6;            // 0..3
  const int quad = lane >> 4;
  const int lm = lane & 15;
  const int a7 = lm & 7;
  const int hd = blockIdx.x;
  const int qg = blockIdx.y >> 1, half = blockIdx.y & 1;
  const int b = blockIdx.z;
  const int bh = b * 16 + hd;
  const size_t hb = (size_t)bh * 2048 * 64;
  const char* khT = (const char*)(kswz + hb);
  const unsigned short* vtT = vtl + (size_t)bh * 32 * 4096;

  half8 qh[4][2];
#pragma unroll
  for (int rg = 0; rg < 4; rg++)
#pragma unroll
    for (int kc = 0; kc < 2; kc++)
      qh[rg][kc] = *(const half8*)(qs + hb
          + (size_t)(qg * 256 + w * 64 + rg * 16 + lm) * 64 + kc * 32 + quad * 8);

  const floatx4 zero4 = {0.f, 0.f, 0.f, 0.f};
  floatx4 O[4][4];
#pragma unroll
  for (int rg = 0; rg < 4; rg++)
#pragma unroll
    for (int dt = 0; dt < 4; dt++) O[rg][dt] = zero4;
  floatx4 racc[4];                   // rsum accumulators (ones-MFMA)
#pragma unroll
  for (int rg = 0; rg < 4; rg++) racc[rg] = zero4;
  const short one_bf = (short)0x3F80;           // bf16 1.0
  const bhalf8 vones = {one_bf, one_bf, one_bf, one_bf,
                        one_bf, one_bf, one_bf, one_bf};

  const int lo16 = lane * 16;
  const size_t g0 = (size_t)half * 16 * 8192;

  // prologue: stage K tile 0 of this half (2 dma16/wave)
#pragma unroll
  for (int r = 0; r < 2; r++) {
    int sb = (w * 2 + r) * 1024;
    dma16(khT + g0 + sb + lo16, (char*)KH[0] + sb);
  }

  for (int t = 0; t < 16; t++) {
    const int cur = t & 1;
    __syncthreads();

    // V fragments global->reg (issued first; PV's vmcnt wait then leaves
    // the younger K-dma prefetch in flight)
    const unsigned short* vb = vtT + ((size_t)(half * 16 + t) * 2) * 2048 + lane * 32;
    bhalf8 vf[2][4];
#pragma unroll
    for (int kc4 = 0; kc4 < 2; kc4++)
#pragma unroll
      for (int dt = 0; dt < 4; dt++)
        vf[kc4][dt] = *(const bhalf8*)(vb + kc4 * 2048 + dt * 8);

    if (t < 15) {
      const size_t gof = g0 + (size_t)(t + 1) * 8192;
#pragma unroll
      for (int r = 0; r < 2; r++) {
        int sb = (w * 2 + r) * 1024;
        dma16(khT + gof + sb + lo16, (char*)KH[cur ^ 1] + sb);
      }
    }

    const half_t* kh_ = KH[cur];

    // K fragments: read ONCE per tile (p-invariant addresses)
    half8 kf[8];
#pragma unroll
    for (int kb = 0; kb < 4; kb++)
#pragma unroll
      for (int kc = 0; kc < 2; kc++) {
        int addr = (kb * 16 + lm) * 64 + (((kc * 4 + quad) ^ a7) << 3);
        kf[kb * 2 + kc] = *(const half8*)&kh_[addr];
      }

#pragma unroll
    for (int p = 0; p < 2; p++) {
      floatx4 s[2][4];
#pragma unroll
      for (int ri = 0; ri < 2; ri++)
#pragma unroll
        for (int kb = 0; kb < 4; kb++) s[ri][kb] = zero4;

      __builtin_amdgcn_s_setprio(1);
#pragma unroll
      for (int kb = 0; kb < 4; kb++)
#pragma unroll
        for (int kc = 0; kc < 2; kc++) {
          // swapped: A = K (rows=keys), B = Q (cols=q-rows)
#pragma unroll
          for (int ri = 0; ri < 2; ri++)
            s[ri][kb] = MFMAF16(kf[kb * 2 + kc], qh[p * 2 + ri][kc], s[ri][kb]);
        }
      __builtin_amdgcn_s_setprio(0);

#pragma unroll
      for (int ri = 0; ri < 2; ri++) {
        const int rg = p * 2 + ri;
        // exp2 of all 16 in-lane scores (q-row lm, keys quad*4+rr+16kb)
        float e[4][4];
#pragma unroll
        for (int kb = 0; kb < 4; kb++)
#pragma unroll
          for (int rr = 0; rr < 4; rr++)
            e[kb][rr] = __builtin_amdgcn_exp2f(s[ri][kb][rr]);

        __builtin_amdgcn_s_setprio(1);
#pragma unroll
        for (int kc4 = 0; kc4 < 2; kc4++) {
          union { unsigned int w4[4]; bhalf8 v; } pa;
          pa.w4[0] = cvtpk_bf16(e[2 * kc4][0],     e[2 * kc4][1]);
          pa.w4[1] = cvtpk_bf16(e[2 * kc4][2],     e[2 * kc4][3]);
          pa.w4[2] = cvtpk_bf16(e[2 * kc4 + 1][0], e[2 * kc4 + 1][1]);
          pa.w4[3] = cvtpk_bf16(e[2 * kc4 + 1][2], e[2 * kc4 + 1][3]);
          racc[rg] = MFMABF16(pa.v, vones, racc[rg]);   // row-sum of P
#pragma unroll
          for (int dt = 0; dt < 4; dt++)
            O[rg][dt] = MFMABF16(pa.v, vf[kc4][dt], O[rg][dt]);
        }
        __builtin_amdgcn_s_setprio(0);
      }
    }
  }

  // epilogue: rsum direct from racc (row = quad*4+rr, same as O) and
  // bf16 O-partials
  unsigned short* op = Opart + (size_t)half * 65536 * 64;
  float* rp = rpart + (size_t)half * 65536;
#pragma unroll
  for (int rg = 0; rg < 4; rg++) {
#pragma unroll
    for (int rr = 0; rr < 4; rr++) {
      int n = qg * 256 + w * 64 + rg * 16 + quad * 4 + rr;
      size_t row = (size_t)bh * 2048 + n;
      if (lm == 0) rp[row] = racc[rg][rr];
#pragma unroll
      for (int dt = 0; dt < 4; dt++)
        op[row * 64 + dt * 16 + lm] = f2bf(O[rg][dt][rr]);
    }
  }
}

// ---------------------------------------------------------------------------
// combine: o = (O0+O1)/(r0+r1) -> obf fp16 [4096,1024] (out-proj A layout)
// ---------------------------------------------------------------------------
__global__ __launch_bounds__(256) void k_combine(const unsigned short* __restrict__ Opart,
                                                 const float* __restrict__ rpart,
                                                 half_t* __restrict__ obf) {
  size_t e = ((size_t)blockIdx.x * 256 + threadIdx.x) * 8;
  size_t row = e >> 6; int d0 = (int)(e & 63);
  float inv = 1.0f / (rpart[row] + rpart[65536 + row]);
  bhalf8 o0 = *(const bhalf8*)&Opart[row * 64 + d0];
  bhalf8 o1 = *(const bhalf8*)&Opart[(size_t)65536 * 64 + row * 64 + d0];
  int b = (int)(row >> 15), h = (int)((row >> 11) & 15), n = (int)(row & 2047);
  half8 o;
#pragma unroll
  for (int j = 0; j < 8; j++)
    o[j] = (half_t)((bf2f((unsigned short)o0[j]) + bf2f((unsigned short)o1[j])) * inv);
  *(half8*)&obf[((size_t)(b * 2048 + n)) * 1024 + h * 64 + d0] = o;
}

// ---------------------------------------------------------------------------
extern "C" void kernel_launch(void* const* d_in, const int* in_sizes, int n_in,
                              void* d_out, int out_size, void* d_ws, size_t ws_size,
                              hipStream_t stream) {
  const float* query = (const float*)d_in[0];
  const float* key_  = (const float*)d_in[1];
  const float* value = (const float*)d_in[2];
  const float* wq  = (const float*)d_in[4];
  const float* wk  = (const float*)d_in[5];
  const float* wv  = (const float*)d_in[6];
  const float* wo  = (const float*)d_in[7];
  const float* wb1 = (const float*)d_in[8];
  const float* wb2 = (const float*)d_in[9];
  const float* wg1 = (const float*)d_in[10];
  const float* wg2 = (const float*)d_in[11];
  const int* nctx  = (const int*)d_in[12];
  float* out = (float*)d_out;

  char* ws = (char*)d_ws;
  size_t o = 0;
  float* base_v = (float*)(ws + o); o += 4096;
  half_t* q16   = (half_t*)(ws + o); o += (size_t)4096 * 1024 * 2;   // later: qs
  half_t* k16   = (half_t*)(ws + o); o += (size_t)4096 * 1024 * 2;   // later: obf
  half_t* v16   = (half_t*)(ws + o); o += (size_t)4096 * 1024 * 2;
  half_t* w16   = (half_t*)(ws + o); o += (size_t)4 * 1024 * 1024 * 2;
  half_t* qp16  = (half_t*)(ws + o); o += (size_t)4096 * 1024 * 2;
  half_t* kswz  = (half_t*)(ws + o); o += (size_t)4096 * 1024 * 2;
  unsigned short* vtl = (unsigned short*)(ws + o); o += (size_t)4096 * 1024 * 2;
  unsigned short* Opart = (unsigned short*)(ws + o); o += (size_t)2 * 65536 * 64 * 2;
  float* rpart = (float*)(ws + o); o += (size_t)2 * 65536 * 4;
  half_t* qs  = q16;    // aliases (q16/k16 dead after k_gemm<0>)
  half_t* obf = k16;

  k_cvtbase<<<8196, 256, 0, stream>>>(query, key_, value, wq, wk, wv, wo,
                                      q16, k16, v16, w16, wb1, wb2, nctx, base_v);
  k_gemm<0><<<dim3(8, 32, 3), 256, 0, stream>>>(q16, w16, qp16, kswz, vtl, nullptr);
  k_gate<<<512, 256, 0, stream>>>(qp16, base_v, wg1, wg2, qs);
  k_attn<<<dim3(16, 16, 2), 256, 0, stream>>>(qs, kswz, vtl, Opart, rpart);
  k_combine<<<2048, 256, 0, stream>>>(Opart, rpart, obf);
  k_gemm<3><<<dim3(8, 32, 1), 256, 0, stream>>>(obf, w16 + (size_t)3 * 1048576,
                                                nullptr, nullptr, nullptr, out);
}